// Round 6
// baseline (4527.679 us; speedup 1.0000x reference)
//
#include <hip/hip_runtime.h>
#include <hip/hip_bf16.h>

constexpr int B   = 4;
constexpr int N   = 1024;
constexpr int D   = 128;
constexpr int KNN = 10;
constexpr int NH  = 4;

// ---------------------------------------------------------------- norm p2d
__global__ __launch_bounds__(256) void k_norm2d(const float* __restrict__ p2d,
                                                float* __restrict__ f2) {
  int i = blockIdx.x * 256 + threadIdx.x;  // over B*N
  const float* p = p2d + (size_t)i * 3;
  float x = p[0], y = p[1], z = p[2];
  float inr = 1.f / sqrtf(x * x + y * y + z * z);
  float* o = f2 + (size_t)i * 3;
  o[0] = x * inr; o[1] = y * inr; o[2] = z * inr;
}

// ---------------------------------------------------------------- KNN encode
__global__ __launch_bounds__(256) void k_encode(const float* __restrict__ pts,
                                                const float* __restrict__ w,
                                                const float* __restrict__ bias,
                                                float* __restrict__ desc) {
  __shared__ float P[N][3];
  __shared__ float xx[N];
  __shared__ float dist[N];
  __shared__ float rv[256];
  __shared__ int   ri[256];
  __shared__ float feat[6];
  __shared__ int   nidx[KNN];
  int t = threadIdx.x;
  int n = blockIdx.x, b = blockIdx.y;
  const float* pb = pts + (size_t)b * N * 3;
  for (int i = t; i < N; i += 256) {
    float x = pb[i * 3 + 0], y = pb[i * 3 + 1], z = pb[i * 3 + 2];
    P[i][0] = x; P[i][1] = y; P[i][2] = z;
    xx[i] = x * x + y * y + z * z;
  }
  __syncthreads();
  float cx = P[n][0], cy = P[n][1], cz = P[n][2], cxx = xx[n];
  for (int i = t; i < N; i += 256) {
    float ip = cx * P[i][0] + cy * P[i][1] + cz * P[i][2];
    dist[i] = 2.f * ip - cxx - xx[i];
  }
  __syncthreads();
  for (int kk = 0; kk < KNN; ++kk) {
    float bv = -3.0e38f; int bi = N;
    for (int i = t; i < N; i += 256) {
      float v = dist[i];
      if (v > bv) { bv = v; bi = i; }
    }
    rv[t] = bv; ri[t] = bi;
    __syncthreads();
    for (int s = 128; s > 0; s >>= 1) {
      if (t < s) {
        float v2 = rv[t + s]; int i2 = ri[t + s];
        if (v2 > rv[t] || (v2 == rv[t] && i2 < ri[t])) { rv[t] = v2; ri[t] = i2; }
      }
      __syncthreads();
    }
    if (t == 0) { nidx[kk] = ri[0]; dist[ri[0]] = -3.0e38f; }
    __syncthreads();
  }
  if (t == 0) {
    float sx = 0, sy = 0, sz = 0;
    for (int kk = 0; kk < KNN; ++kk) {
      int i = nidx[kk];
      sx += P[i][0]; sy += P[i][1]; sz += P[i][2];
    }
    const float invk = 1.f / KNN;
    feat[0] = sx * invk - cx; feat[1] = sy * invk - cy; feat[2] = sz * invk - cz;
    feat[3] = cx; feat[4] = cy; feat[5] = cz;
  }
  __syncthreads();
  if (t < D) {
    const float* wr = w + t * 6;
    float a = bias[t];
#pragma unroll
    for (int j = 0; j < 6; ++j) a += wr[j] * feat[j];
    desc[((size_t)b * D + t) * N + n] = a;
  }
}

// ---------------------------------------------------------------- fused QKV conv
// grid (N/256, 48, 2*B): blockIdx.y = seg*16 + o-group (8 outputs).
__global__ __launch_bounds__(256) void k_qkv(const float* __restrict__ desc,
                                             const float* __restrict__ pw,
                                             const float* __restrict__ pb,
                                             float* __restrict__ Qb,
                                             float* __restrict__ Kb,
                                             float* __restrict__ Vb,
                                             int cross) {
  int n = blockIdx.x * 256 + threadIdx.x;
  int gy = blockIdx.y;
  int seg = gy >> 4;            // 0=Q, 1=K, 2=V
  int o0 = (gy & 15) * 8;
  int z = blockIdx.z;           // s*B + b
  int s = z >> 2, b = z & 3;
  int si = (seg == 0) ? s : (cross ? 1 - s : s);
  const float* ip = desc + ((size_t)si * B + b) * (size_t)(D * N);
  const float* w0 = pw + (size_t)seg * D * D + (size_t)o0 * D;
  const float* bp = pb + seg * D + o0;
  float a[8];
#pragma unroll
  for (int i = 0; i < 8; ++i) a[i] = bp[i];
#pragma unroll 2
  for (int c = 0; c < D; ++c) {
    float v = ip[(size_t)c * N + n];
#pragma unroll
    for (int i = 0; i < 8; ++i) a[i] = fmaf(w0[i * D + c], v, a[i]);
  }
  float* out = (seg == 0) ? Qb : (seg == 1) ? Kb : Vb;
  size_t ob = ((size_t)z * D + o0) * N + n;
#pragma unroll
  for (int i = 0; i < 8; ++i) out[ob + (size_t)i * N] = a[i];
}

// ---------------------------------------------------------------- generic conv1 (8-o unroll)
// grid (N/256, Cout/8, 2*B)
__global__ __launch_bounds__(256) void k_conv(const float* __restrict__ in0,
                                              const float* __restrict__ in1,
                                              const float* __restrict__ cat0,
                                              const float* __restrict__ cat1,
                                              const float* __restrict__ w,
                                              const float* __restrict__ bias,
                                              const float* __restrict__ res,
                                              float* __restrict__ out,
                                              int Cin, int catOff,
                                              size_t in_bstr, size_t cat_bstr,
                                              int Cout) {
  int n = blockIdx.x * 256 + threadIdx.x;
  int o0 = blockIdx.y * 8;
  int z = blockIdx.z;           // s*B + b
  int s = z >> 2, b = z & 3;
  const float* ip = (s ? in1 : in0) + (size_t)b * in_bstr;
  const float* w0 = w + (size_t)o0 * Cin;
  float a[8];
#pragma unroll
  for (int i = 0; i < 8; ++i) a[i] = bias[o0 + i];
#pragma unroll 2
  for (int c = 0; c < catOff; ++c) {
    float v = ip[(size_t)c * N + n];
#pragma unroll
    for (int i = 0; i < 8; ++i) a[i] = fmaf(w0[i * Cin + c], v, a[i]);
  }
  if (cat0) {
    const float* cp = (s ? cat1 : cat0) + (size_t)b * cat_bstr;
#pragma unroll 2
    for (int c = catOff; c < Cin; ++c) {
      float v = cp[(size_t)(c - catOff) * N + n];
#pragma unroll
      for (int i = 0; i < 8; ++i) a[i] = fmaf(w0[i * Cin + c], v, a[i]);
    }
  }
  size_t ob = ((size_t)z * Cout + o0) * N + n;
  if (res) {
#pragma unroll
    for (int i = 0; i < 8; ++i) a[i] += res[ob + (size_t)i * N];
  }
#pragma unroll
  for (int i = 0; i < 8; ++i) out[ob + (size_t)i * N] = a[i];
}

// ---------------------------------------------------------------- attention v6
// grid (N/64, NH, 2*B) = 512 blocks, 256 thr = 4 waves. Wave s owns keys
// [s*256,(s+1)*256) for the block's 64 queries (1 query/lane). K/V read
// DIRECTLY from global with wave-uniform addresses (readfirstlane wave id ->
// scalar/broadcast loads through L1/L2; zero LDS in the K-loop; K/V tile had
// no reuse so LDS staging was a pure middleman). LDS only for the 4-way merge.
__global__ __launch_bounds__(256) void k_attn(const float* __restrict__ Q,
                                              const float* __restrict__ Kt,
                                              const float* __restrict__ Vt,
                                              float* __restrict__ O) {
  __shared__ float acc_s[4 * 64 * 33];   // 33.8 KB
  __shared__ float ms_[4][64], ls_[4][64];
  const int t  = threadIdx.x;
  const int lq = t & 63;
  const int sW = __builtin_amdgcn_readfirstlane(t >> 6);  // wave id, SGPR
  const int q0 = blockIdx.x * 64;
  const int h  = blockIdx.y;
  const int z  = blockIdx.z;
  const size_t base = (size_t)z * (size_t)(D * N);
  const float* Kh = Kt + base + (size_t)h * N;   // dim d row at + d*4*N
  const float* Vh = Vt + base + (size_t)h * N;
  const float scale = 0.17677669529663687f;      // 1/sqrt(32), folded into q

  float q[32], acc[32];
#pragma unroll
  for (int d = 0; d < 32; ++d) {
    q[d] = Q[base + (size_t)(d * 4 + h) * N + q0 + lq] * scale;
    acc[d] = 0.f;
  }
  float mx = -1e30f, l = 0.f;

  for (int c = 0; c < 8; ++c) {
    const int k0 = sW * 256 + c * 32;
#pragma unroll
    for (int grp = 0; grp < 4; ++grp) {
      float sc[8];
#pragma unroll
      for (int jg = 0; jg < 2; ++jg) {
        const int j0 = k0 + grp * 8 + jg * 4;    // wave-uniform
        float a0 = 0, a1 = 0, a2 = 0, a3 = 0;
#pragma unroll
        for (int d = 0; d < 32; ++d) {
          const float4 kv = *(const float4*)(Kh + (size_t)(d * 4) * N + j0);
          a0 = fmaf(q[d], kv.x, a0); a1 = fmaf(q[d], kv.y, a1);
          a2 = fmaf(q[d], kv.z, a2); a3 = fmaf(q[d], kv.w, a3);
        }
        sc[jg * 4 + 0] = a0; sc[jg * 4 + 1] = a1;
        sc[jg * 4 + 2] = a2; sc[jg * 4 + 3] = a3;
      }
      // online softmax over these 8 keys
      float hm = sc[0];
#pragma unroll
      for (int j = 1; j < 8; ++j) hm = fmaxf(hm, sc[j]);
      float nm = fmaxf(mx, hm);
      float cr = __expf(mx - nm);
      l *= cr;
#pragma unroll
      for (int d = 0; d < 32; ++d) acc[d] *= cr;
      mx = nm;
#pragma unroll
      for (int j = 0; j < 8; ++j) { sc[j] = __expf(sc[j] - mx); l += sc[j]; }
      // PV
#pragma unroll
      for (int jg = 0; jg < 2; ++jg) {
        const int j0 = k0 + grp * 8 + jg * 4;
        float p0 = sc[jg * 4 + 0], p1 = sc[jg * 4 + 1];
        float p2 = sc[jg * 4 + 2], p3 = sc[jg * 4 + 3];
#pragma unroll
        for (int d = 0; d < 32; ++d) {
          const float4 v = *(const float4*)(Vh + (size_t)(d * 4) * N + j0);
          acc[d] = fmaf(p0, v.x, fmaf(p1, v.y, fmaf(p2, v.z, fmaf(p3, v.w, acc[d]))));
        }
      }
    }
  }

  // ---- merge 4 key-split partials
  ms_[sW][lq] = mx; ls_[sW][lq] = l;
#pragma unroll
  for (int d = 0; d < 32; ++d) acc_s[(sW * 64 + lq) * 33 + d] = acc[d];
  __syncthreads();
  {
    int qq = t & 63, dh = t >> 6;
    float M = fmaxf(fmaxf(ms_[0][qq], ms_[1][qq]), fmaxf(ms_[2][qq], ms_[3][qq]));
    float wg[4], L = 0.f;
#pragma unroll
    for (int ss = 0; ss < 4; ++ss) {
      wg[ss] = __expf(ms_[ss][qq] - M);
      L += ls_[ss][qq] * wg[ss];
    }
    float invL = 1.f / L;
#pragma unroll
    for (int k = 0; k < 8; ++k) {
      int d = dh * 8 + k;
      float o = 0.f;
#pragma unroll
      for (int ss = 0; ss < 4; ++ss) o += acc_s[(ss * 64 + qq) * 33 + d] * wg[ss];
      O[base + (size_t)(d * 4 + h) * N + q0 + qq] = o * invL;
    }
  }
}

// ---------------------------------------------------------------- BN stats (single pass)
__global__ __launch_bounds__(256) void k_bnstat(const float* __restrict__ h,
                                                float* __restrict__ stat) {
  int c = blockIdx.x, s = blockIdx.y, t = threadIdx.x;
  __shared__ float red[256], red2[256];
  const float* base = h + ((size_t)s * B * 256 + c) * N;
  float sum = 0, sq = 0;
  for (int b = 0; b < B; ++b)
    for (int i = t; i < N; i += 256) {
      float v = base[(size_t)b * 256 * N + i];
      sum += v; sq = fmaf(v, v, sq);
    }
  red[t] = sum; red2[t] = sq; __syncthreads();
  for (int sft = 128; sft > 0; sft >>= 1) {
    if (t < sft) { red[t] += red[t + sft]; red2[t] += red2[t + sft]; }
    __syncthreads();
  }
  if (t == 0) {
    float mean = red[0] / (float)(B * N);
    float var = fmaxf(red2[0] / (float)(B * N) - mean * mean, 0.f);
    stat[(s * 256 + c) * 2 + 0] = mean;
    stat[(s * 256 + c) * 2 + 1] = 1.f / sqrtf(var + 1e-5f);
  }
}

// ---------------------------------------------------------------- mlp2 with fused BN+ReLU + residual
// grid (N/256, 16, 2*B)
__global__ __launch_bounds__(256) void k_mlp2(const float* __restrict__ hb,
                                              const float* __restrict__ stat,
                                              const float* __restrict__ g,
                                              const float* __restrict__ bt,
                                              const float* __restrict__ w,
                                              const float* __restrict__ bias,
                                              const float* __restrict__ res,
                                              float* __restrict__ out) {
  int n = blockIdx.x * 256 + threadIdx.x;
  int o0 = blockIdx.y * 8;
  int z = blockIdx.z;
  int s = z >> 2;
  const float* hp = hb + (size_t)z * 256 * N;
  const float* w0 = w + (size_t)o0 * 256;
  const float* st = stat + (size_t)s * 256 * 2;
  float a[8];
#pragma unroll
  for (int i = 0; i < 8; ++i) a[i] = bias[o0 + i];
#pragma unroll 2
  for (int c = 0; c < 256; ++c) {
    float A = st[c * 2 + 1] * g[c];
    float Bc = fmaf(-st[c * 2 + 0], A, bt[c]);
    float v = fmaxf(fmaf(hp[(size_t)c * N + n], A, Bc), 0.f);
#pragma unroll
    for (int i = 0; i < 8; ++i) a[i] = fmaf(w0[i * 256 + c], v, a[i]);
  }
  size_t ob = ((size_t)z * D + o0) * N + n;
#pragma unroll
  for (int i = 0; i < 8; ++i) out[ob + (size_t)i * N] = a[i] + res[ob + (size_t)i * N];
}

// ---------------------------------------------------------------- pairwise dist (8-m tile)
__global__ __launch_bounds__(256) void k_dist(const float* __restrict__ d0,
                                              const float* __restrict__ d1,
                                              float* __restrict__ la) {
  __shared__ float xm[8][128];
  __shared__ float n0s[8];
  int m0 = blockIdx.x * 8, b = blockIdx.y, t = threadIdx.x;
  const float* p0 = d0 + (size_t)b * D * N;
  const float* p1 = d1 + (size_t)b * D * N;
  for (int i = t; i < 8 * 128; i += 256) {
    int mm = i >> 7, d = i & 127;
    xm[mm][d] = p0[(size_t)d * N + m0 + mm];
  }
  __syncthreads();
  if (t < 8) {
    float s = 0;
    for (int d = 0; d < 128; ++d) s += xm[t][d] * xm[t][d];
    n0s[t] = s;
  }
  __syncthreads();
  float dot[8][4] = {{0}};
  float n1[4] = {0, 0, 0, 0};
  for (int d = 0; d < 128; ++d) {
    float v[4];
#pragma unroll
    for (int u = 0; u < 4; ++u) {
      v[u] = p1[(size_t)d * N + t + u * 256];
      n1[u] = fmaf(v[u], v[u], n1[u]);
    }
#pragma unroll
    for (int mm = 0; mm < 8; ++mm) {
      float x = xm[mm][d];
#pragma unroll
      for (int u = 0; u < 4; ++u) dot[mm][u] = fmaf(x, v[u], dot[mm][u]);
    }
  }
  for (int mm = 0; mm < 8; ++mm) {
    float* row = la + ((size_t)b * N + m0 + mm) * N;
#pragma unroll
    for (int u = 0; u < 4; ++u) {
      float dist2 = fmaxf(n0s[mm] + n1[u] - 2.f * dot[mm][u], 1e-30f);
      row[t + u * 256] = -sqrtf(dist2);
    }
  }
}

// ---------------------------------------------------------------- sinkhorn row (+ pending col sub)
__global__ __launch_bounds__(256) void k_row_lse(float* __restrict__ la,
                                                 const float* __restrict__ colse) {
  __shared__ float red[256];
  int t = threadIdx.x;
  int bm = blockIdx.x;              // over B*N
  int b = bm >> 10;
  float* row = la + (size_t)bm * N;
  float v0 = row[t], v1 = row[t + 256], v2 = row[t + 512], v3 = row[t + 768];
  if (colse) {
    const float* cl = colse + (size_t)b * N;
    v0 -= cl[t]; v1 -= cl[t + 256]; v2 -= cl[t + 512]; v3 -= cl[t + 768];
  }
  float mx = fmaxf(fmaxf(v0, v1), fmaxf(v2, v3));
  red[t] = mx; __syncthreads();
  for (int s = 128; s > 0; s >>= 1) {
    if (t < s) red[t] = fmaxf(red[t], red[t + s]);
    __syncthreads();
  }
  mx = red[0]; __syncthreads();
  float se = __expf(v0 - mx) + __expf(v1 - mx) + __expf(v2 - mx) + __expf(v3 - mx);
  red[t] = se; __syncthreads();
  for (int s = 128; s > 0; s >>= 1) {
    if (t < s) red[t] += red[t + s];
    __syncthreads();
  }
  float lse = mx + __logf(red[0]);
  row[t] = v0 - lse; row[t + 256] = v1 - lse;
  row[t + 512] = v2 - lse; row[t + 768] = v3 - lse;
}

// ---------------------------------------------------------------- sinkhorn col (16 partials)
__global__ __launch_bounds__(256) void k_col_part(const float* __restrict__ la,
                                                  float* __restrict__ pmax,
                                                  float* __restrict__ psum) {
  int t = threadIdx.x;
  int n = blockIdx.x * 256 + t;
  int p = blockIdx.y, b = blockIdx.z;
  const float* base = la + ((size_t)b * N + p * 64) * N + n;
  float mx = -1e30f, s = 0;
  for (int m = 0; m < 64; ++m) {
    float v = base[(size_t)m * N];
    if (v > mx) { s = s * __expf(mx - v) + 1.f; mx = v; }
    else s += __expf(v - mx);
  }
  pmax[((size_t)b * 16 + p) * N + n] = mx;
  psum[((size_t)b * 16 + p) * N + n] = s;
}

__global__ __launch_bounds__(256) void k_col_fin(const float* __restrict__ pmax,
                                                 const float* __restrict__ psum,
                                                 float* __restrict__ lse) {
  int i = blockIdx.x * 256 + threadIdx.x;  // over B*N
  int b = i / N, n = i % N;
  float mx = -1e30f;
#pragma unroll
  for (int p = 0; p < 16; ++p) mx = fmaxf(mx, pmax[((size_t)b * 16 + p) * N + n]);
  float s = 0;
#pragma unroll
  for (int p = 0; p < 16; ++p)
    s += psum[((size_t)b * 16 + p) * N + n] * __expf(pmax[((size_t)b * 16 + p) * N + n] - mx);
  lse[i] = mx + __logf(s);
}

// ---------------------------------------------------------------- rodrigues + transform
__global__ __launch_bounds__(256) void k_rod(const float* __restrict__ pose,
                                             const float* __restrict__ p3d,
                                             float* __restrict__ p3dt) {
  int b = blockIdx.y;
  int n = blockIdx.x * 256 + threadIdx.x;
  const float* aa = pose + b * 6;
  float ax = aa[0], ay = aa[1], az = aa[2];
  float th = fmaxf(sqrtf(ax * ax + ay * ay + az * az), 1e-8f);
  float rx = ax / th, ry = ay / th, rz = az / th;
  float c = cosf(th), s = sinf(th), oc = 1.f - c;
  float R00 = c + oc * rx * rx,      R01 = oc * rx * ry - s * rz, R02 = oc * rx * rz + s * ry;
  float R10 = oc * ry * rx + s * rz, R11 = c + oc * ry * ry,      R12 = oc * ry * rz - s * rx;
  float R20 = oc * rz * rx - s * ry, R21 = oc * rz * ry + s * rx, R22 = c + oc * rz * rz;
  const float* p = p3d + ((size_t)b * N + n) * 3;
  float x = p[0], y = p[1], z = p[2];
  float X = R00 * x + R01 * y + R02 * z + aa[3];
  float Y = R10 * x + R11 * y + R12 * z + aa[4];
  float Z = R20 * x + R21 * y + R22 * z + aa[5];
  float inr = 1.f / sqrtf(X * X + Y * Y + Z * Z);
  float* o = p3dt + ((size_t)b * N + n) * 3;
  o[0] = X * inr; o[1] = Y * inr; o[2] = Z * inr;
}

// ---------------------------------------------------------------- final error
__global__ __launch_bounds__(256) void k_err(const float* __restrict__ la,
                                             const float* __restrict__ colse,
                                             const float* __restrict__ f2,
                                             const float* __restrict__ p3dt,
                                             float* __restrict__ rowsum) {
  __shared__ float red[256];
  int m = blockIdx.x, b = blockIdx.y, t = threadIdx.x;
  const float* row = la + ((size_t)b * N + m) * N;
  const float* cl = colse + (size_t)b * N;
  const float* f = f2 + ((size_t)b * N + m) * 3;
  float fx = f[0], fy = f[1], fz = f[2];
  float s = 0;
  for (int n = t; n < N; n += 256) {
    const float* pp = p3dt + ((size_t)b * N + n) * 3;
    float dot = fx * pp[0] + fy * pp[1] + fz * pp[2];
    s += __expf(row[n] - cl[n]) * (1.f - dot);
  }
  red[t] = s; __syncthreads();
  for (int sft = 128; sft > 0; sft >>= 1) {
    if (t < sft) red[t] += red[t + sft];
    __syncthreads();
  }
  if (t == 0) rowsum[(size_t)b * N + m] = red[0];
}

__global__ __launch_bounds__(256) void k_err_fin(const float* __restrict__ rowsum,
                                                 float* __restrict__ out) {
  __shared__ float red[256];
  int b = blockIdx.x, t = threadIdx.x;
  float s = 0;
  for (int i = t; i < N; i += 256) s += rowsum[(size_t)b * N + i];
  red[t] = s; __syncthreads();
  for (int sft = 128; sft > 0; sft >>= 1) {
    if (t < sft) red[t] += red[t + sft];
    __syncthreads();
  }
  if (t == 0) out[b] = red[0];
}

// ================================================================= host
extern "C" void kernel_launch(void* const* d_in, const int* in_sizes, int n_in,
                              void* d_out, int out_size, void* d_ws, size_t ws_size,
                              hipStream_t stream) {
  const float* p2d     = (const float*)d_in[0];
  const float* p3d     = (const float*)d_in[1];
  const float* pose    = (const float*)d_in[2];
  const float* enc2d_w = (const float*)d_in[3];
  const float* enc2d_b = (const float*)d_in[4];
  const float* enc3d_w = (const float*)d_in[5];
  const float* enc3d_b = (const float*)d_in[6];
  const float* proj_w  = (const float*)d_in[7];
  const float* proj_b  = (const float*)d_in[8];
  const float* merge_w = (const float*)d_in[9];
  const float* merge_b = (const float*)d_in[10];
  const float* mlp1_w  = (const float*)d_in[11];
  const float* mlp1_b  = (const float*)d_in[12];
  const float* bn_g    = (const float*)d_in[13];
  const float* bn_b    = (const float*)d_in[14];
  const float* mlp2_w  = (const float*)d_in[15];
  const float* mlp2_b  = (const float*)d_in[16];

  float* W = (float*)d_ws;
  size_t off = 0;
  auto alloc = [&](size_t nelem) { float* p = W + off; off += nelem; return p; };
  const size_t SET = (size_t)B * D * N;
  float* f2    = alloc((size_t)B * N * 3);
  float* p3dt  = alloc((size_t)B * N * 3);
  float* descA = alloc(2 * SET);
  float* descB = alloc(2 * SET);
  float* Qb    = alloc(2 * SET);
  float* Kb    = alloc(2 * SET);
  float* Vb    = alloc(2 * SET);
  float* attnb = alloc(2 * SET);
  float* msgb  = alloc(2 * SET);
  float* hb    = alloc((size_t)2 * B * 256 * N);
  float* stat  = alloc(2 * 256 * 2);
  float* la    = alloc((size_t)B * N * N);
  float* pmax  = alloc((size_t)B * 16 * N);
  float* psum  = alloc((size_t)B * 16 * N);
  float* lseb  = alloc((size_t)B * N);
  float* rowsum= alloc((size_t)B * N);
  (void)ws_size; (void)in_sizes; (void)n_in; (void)out_size;

  auto conv = [&](const float* in0, const float* in1, const float* cat0,
                  const float* cat1, const float* w, const float* bias,
                  const float* res, float* out, int Cin, int catOff,
                  size_t in_bstr, size_t cat_bstr, int Cout) {
    dim3 g(N / 256, Cout / 8, 2 * B);
    k_conv<<<g, 256, 0, stream>>>(in0, in1, cat0, cat1, w, bias, res, out,
                                  Cin, catOff, in_bstr, cat_bstr, Cout);
  };

  k_norm2d<<<(B * N) / 256, 256, 0, stream>>>(p2d, f2);
  k_encode<<<dim3(N, B), 256, 0, stream>>>(f2, enc2d_w, enc2d_b, descA);
  k_encode<<<dim3(N, B), 256, 0, stream>>>(p3d, enc3d_w, enc3d_b, descA + SET);

  float* dc = descA;
  float* dn = descB;
  for (int i = 0; i < 6; ++i) {
    int cross = (i & 1);
    const float* pw = proj_w + (size_t)i * 3 * D * D;
    const float* pb = proj_b + (size_t)i * 3 * D;
    k_qkv<<<dim3(N / 256, 48, 2 * B), 256, 0, stream>>>(dc, pw, pb, Qb, Kb, Vb, cross);
    k_attn<<<dim3(N / 64, NH, 2 * B), 256, 0, stream>>>(Qb, Kb, Vb, attnb);
    conv(attnb, attnb + SET, nullptr, nullptr, merge_w + (size_t)i * D * D,
         merge_b + (size_t)i * D, nullptr, msgb, D, D, (size_t)D * N, 0, D);
    conv(dc, dc + SET, msgb, msgb + SET, mlp1_w + (size_t)i * 256 * 256,
         mlp1_b + (size_t)i * 256, nullptr, hb, 256, 128, (size_t)D * N,
         (size_t)D * N, 256);
    k_bnstat<<<dim3(256, 2), 256, 0, stream>>>(hb, stat);
    k_mlp2<<<dim3(N / 256, 16, 2 * B), 256, 0, stream>>>(
        hb, stat, bn_g + (size_t)i * 256, bn_b + (size_t)i * 256,
        mlp2_w + (size_t)i * D * 256, mlp2_b + (size_t)i * D, dc, dn);
    float* tmp = dc; dc = dn; dn = tmp;
  }

  k_dist<<<dim3(N / 8, B), 256, 0, stream>>>(dc, dc + SET, la);
  for (int it = 0; it < 10; ++it) {
    k_row_lse<<<B * N, 256, 0, stream>>>(la, it == 0 ? nullptr : lseb);
    k_col_part<<<dim3(N / 256, 16, B), 256, 0, stream>>>(la, pmax, psum);
    k_col_fin<<<(B * N) / 256, 256, 0, stream>>>(pmax, psum, lseb);
  }
  k_rod<<<dim3(N / 256, B), 256, 0, stream>>>(pose, p3d, p3dt);
  k_err<<<dim3(N, B), 256, 0, stream>>>(la, lseb, f2, p3dt, rowsum);
  k_err_fin<<<B, 256, 0, stream>>>(rowsum, (float*)d_out);
}

// Round 7
// 2215.389 us; speedup vs baseline: 2.0437x; 2.0437x over previous
//
#include <hip/hip_runtime.h>
#include <hip/hip_bf16.h>

constexpr int B   = 4;
constexpr int N   = 1024;
constexpr int D   = 128;
constexpr int KNN = 10;
constexpr int NH  = 4;

// ---------------------------------------------------------------- norm p2d
__global__ __launch_bounds__(256) void k_norm2d(const float* __restrict__ p2d,
                                                float* __restrict__ f2) {
  int i = blockIdx.x * 256 + threadIdx.x;  // over B*N
  const float* p = p2d + (size_t)i * 3;
  float x = p[0], y = p[1], z = p[2];
  float inr = 1.f / sqrtf(x * x + y * y + z * z);
  float* o = f2 + (size_t)i * 3;
  o[0] = x * inr; o[1] = y * inr; o[2] = z * inr;
}

// ---------------------------------------------------------------- KNN encode
__global__ __launch_bounds__(256) void k_encode(const float* __restrict__ pts,
                                                const float* __restrict__ w,
                                                const float* __restrict__ bias,
                                                float* __restrict__ desc) {
  __shared__ float P[N][3];
  __shared__ float xx[N];
  __shared__ float dist[N];
  __shared__ float rv[256];
  __shared__ int   ri[256];
  __shared__ float feat[6];
  __shared__ int   nidx[KNN];
  int t = threadIdx.x;
  int n = blockIdx.x, b = blockIdx.y;
  const float* pb = pts + (size_t)b * N * 3;
  for (int i = t; i < N; i += 256) {
    float x = pb[i * 3 + 0], y = pb[i * 3 + 1], z = pb[i * 3 + 2];
    P[i][0] = x; P[i][1] = y; P[i][2] = z;
    xx[i] = x * x + y * y + z * z;
  }
  __syncthreads();
  float cx = P[n][0], cy = P[n][1], cz = P[n][2], cxx = xx[n];
  for (int i = t; i < N; i += 256) {
    float ip = cx * P[i][0] + cy * P[i][1] + cz * P[i][2];
    dist[i] = 2.f * ip - cxx - xx[i];
  }
  __syncthreads();
  for (int kk = 0; kk < KNN; ++kk) {
    float bv = -3.0e38f; int bi = N;
    for (int i = t; i < N; i += 256) {
      float v = dist[i];
      if (v > bv) { bv = v; bi = i; }
    }
    rv[t] = bv; ri[t] = bi;
    __syncthreads();
    for (int s = 128; s > 0; s >>= 1) {
      if (t < s) {
        float v2 = rv[t + s]; int i2 = ri[t + s];
        if (v2 > rv[t] || (v2 == rv[t] && i2 < ri[t])) { rv[t] = v2; ri[t] = i2; }
      }
      __syncthreads();
    }
    if (t == 0) { nidx[kk] = ri[0]; dist[ri[0]] = -3.0e38f; }
    __syncthreads();
  }
  if (t == 0) {
    float sx = 0, sy = 0, sz = 0;
    for (int kk = 0; kk < KNN; ++kk) {
      int i = nidx[kk];
      sx += P[i][0]; sy += P[i][1]; sz += P[i][2];
    }
    const float invk = 1.f / KNN;
    feat[0] = sx * invk - cx; feat[1] = sy * invk - cy; feat[2] = sz * invk - cz;
    feat[3] = cx; feat[4] = cy; feat[5] = cz;
  }
  __syncthreads();
  if (t < D) {
    const float* wr = w + t * 6;
    float a = bias[t];
#pragma unroll
    for (int j = 0; j < 6; ++j) a += wr[j] * feat[j];
    desc[((size_t)b * D + t) * N + n] = a;
  }
}

// ---------------------------------------------------------------- fused QKV conv (16-o groups)
// grid (N/256, 24, 2*B): blockIdx.y = seg*8 + o-group (16 outputs).
__global__ __launch_bounds__(256) void k_qkv(const float* __restrict__ desc,
                                             const float* __restrict__ pw,
                                             const float* __restrict__ pb,
                                             float* __restrict__ Qb,
                                             float* __restrict__ Kb,
                                             float* __restrict__ Vb,
                                             int cross) {
  int n = blockIdx.x * 256 + threadIdx.x;
  int gy = blockIdx.y;
  int seg = gy >> 3;            // 0=Q, 1=K, 2=V
  int o0 = (gy & 7) * 16;
  int z = blockIdx.z;           // s*B + b
  int s = z >> 2, b = z & 3;
  int si = (seg == 0) ? s : (cross ? 1 - s : s);
  const float* ip = desc + ((size_t)si * B + b) * (size_t)(D * N);
  const float* w0 = pw + (size_t)seg * D * D + (size_t)o0 * D;
  const float* bp = pb + seg * D + o0;
  float a[16];
#pragma unroll
  for (int i = 0; i < 16; ++i) a[i] = bp[i];
#pragma unroll 2
  for (int c = 0; c < D; ++c) {
    float v = ip[(size_t)c * N + n];
#pragma unroll
    for (int i = 0; i < 16; ++i) a[i] = fmaf(w0[i * D + c], v, a[i]);
  }
  float* out = (seg == 0) ? Qb : (seg == 1) ? Kb : Vb;
  size_t ob = ((size_t)z * D + o0) * N + n;
#pragma unroll
  for (int i = 0; i < 16; ++i) out[ob + (size_t)i * N] = a[i];
}

// ---------------------------------------------------------------- generic conv1 (16-o unroll)
// grid (N/256, Cout/16, 2*B)
__global__ __launch_bounds__(256) void k_conv(const float* __restrict__ in0,
                                              const float* __restrict__ in1,
                                              const float* __restrict__ cat0,
                                              const float* __restrict__ cat1,
                                              const float* __restrict__ w,
                                              const float* __restrict__ bias,
                                              const float* __restrict__ res,
                                              float* __restrict__ out,
                                              int Cin, int catOff,
                                              size_t in_bstr, size_t cat_bstr,
                                              int Cout) {
  int n = blockIdx.x * 256 + threadIdx.x;
  int o0 = blockIdx.y * 16;
  int z = blockIdx.z;           // s*B + b
  int s = z >> 2, b = z & 3;
  const float* ip = (s ? in1 : in0) + (size_t)b * in_bstr;
  const float* w0 = w + (size_t)o0 * Cin;
  float a[16];
#pragma unroll
  for (int i = 0; i < 16; ++i) a[i] = bias[o0 + i];
#pragma unroll 2
  for (int c = 0; c < catOff; ++c) {
    float v = ip[(size_t)c * N + n];
#pragma unroll
    for (int i = 0; i < 16; ++i) a[i] = fmaf(w0[i * Cin + c], v, a[i]);
  }
  if (cat0) {
    const float* cp = (s ? cat1 : cat0) + (size_t)b * cat_bstr;
#pragma unroll 2
    for (int c = catOff; c < Cin; ++c) {
      float v = cp[(size_t)(c - catOff) * N + n];
#pragma unroll
      for (int i = 0; i < 16; ++i) a[i] = fmaf(w0[i * Cin + c], v, a[i]);
    }
  }
  size_t ob = ((size_t)z * Cout + o0) * N + n;
  if (res) {
#pragma unroll
    for (int i = 0; i < 16; ++i) a[i] += res[ob + (size_t)i * N];
  }
#pragma unroll
  for (int i = 0; i < 16; ++i) out[ob + (size_t)i * N] = a[i];
}

// ---------------------------------------------------------------- attention v5 (REVERT: 116us verified)
// grid (N/128, NH, 2*B), 256 thr = 4 waves. Wave s owns keys [s*256,(s+1)*256).
// Each lane owns TWO queries (lq, lq+64). K/V chunks of 32 keys staged per-wave
// in a SINGLE LDS buffer (contiguous float4 writes, broadcast b128 reads feed
// 8 FMAs each); NO barriers in the K-loop (wave-local LDS ordering).
// R6 lesson: direct wave-uniform global loads are 4.5x SLOWER (VMEM latency,
// no ds_read pipelining) — LDS staging is NOT a removable middleman.
// R4 lesson: no min-waves bound (needs ~176 VGPR; (256,2) caps at 128 -> spill).
__global__ __launch_bounds__(256) void k_attn(const float* __restrict__ Q,
                                              const float* __restrict__ Kt,
                                              const float* __restrict__ Vt,
                                              float* __restrict__ O) {
  __shared__ float pool[16896];          // staging 4*2048; merge 4*128*33
  __shared__ float ms_[4][128], ls_[4][128];
  const int t  = threadIdx.x;
  const int lq = t & 63, s = t >> 6;
  const int q0 = blockIdx.x * 128;
  const int h  = blockIdx.y;
  const int z  = blockIdx.z;
  const size_t base = (size_t)z * (size_t)(D * N);
  const float* Kb = Kt + base;
  const float* Vb = Vt + base;
  const int sb    = s * 2048;           // per-wave staging region (single buf)
  const int wrow  = lq >> 3;            // 0..7
  const int wslot = (lq & 7) * 4;       // 0,4,..28

  const float scale = 0.17677669529663687f;  // 1/sqrt(32), folded into q
  float qA[32], qB[32], accA[32], accB[32];
#pragma unroll
  for (int d = 0; d < 32; ++d) {
    qA[d] = Q[base + (size_t)(d * 4 + h) * N + q0 + lq] * scale;
    qB[d] = Q[base + (size_t)(d * 4 + h) * N + q0 + 64 + lq] * scale;
    accA[d] = 0.f; accB[d] = 0.f;
  }
  float mxA = -1e30f, mxB = -1e30f, lA = 0.f, lB = 0.f;

  for (int c = 0; c < 8; ++c) {
    const int k0 = s * 256 + c * 32;
    // stage 32 keys x (32 K-dims + 32 V-dims), contiguous writes, wave-local
#pragma unroll
    for (int it = 0; it < 8; ++it) {
      int row = it * 8 + wrow;
      const float* src = (row < 32) ? (Kb + (size_t)(row * 4 + h) * N)
                                    : (Vb + (size_t)((row - 32) * 4 + h) * N);
      *(float4*)&pool[sb + row * 32 + wslot] = *(const float4*)(src + k0 + wslot);
    }
#pragma unroll
    for (int grp = 0; grp < 4; ++grp) {
      float scA[8], scB[8];
#pragma unroll
      for (int jg = 0; jg < 2; ++jg) {
        const int j0 = grp * 8 + jg * 4;
        float a0 = 0, a1 = 0, a2 = 0, a3 = 0, b0 = 0, b1 = 0, b2 = 0, b3 = 0;
#pragma unroll
        for (int d = 0; d < 32; ++d) {
          const float4 kv = *(const float4*)&pool[sb + d * 32 + j0];
          a0 = fmaf(qA[d], kv.x, a0); a1 = fmaf(qA[d], kv.y, a1);
          a2 = fmaf(qA[d], kv.z, a2); a3 = fmaf(qA[d], kv.w, a3);
          b0 = fmaf(qB[d], kv.x, b0); b1 = fmaf(qB[d], kv.y, b1);
          b2 = fmaf(qB[d], kv.z, b2); b3 = fmaf(qB[d], kv.w, b3);
        }
        scA[jg * 4 + 0] = a0; scA[jg * 4 + 1] = a1;
        scA[jg * 4 + 2] = a2; scA[jg * 4 + 3] = a3;
        scB[jg * 4 + 0] = b0; scB[jg * 4 + 1] = b1;
        scB[jg * 4 + 2] = b2; scB[jg * 4 + 3] = b3;
      }
      // online softmax over these 8 keys
      float hA = scA[0], hB = scB[0];
#pragma unroll
      for (int j = 1; j < 8; ++j) { hA = fmaxf(hA, scA[j]); hB = fmaxf(hB, scB[j]); }
      float nmA = fmaxf(mxA, hA), nmB = fmaxf(mxB, hB);
      float cA = __expf(mxA - nmA), cB = __expf(mxB - nmB);
      lA *= cA; lB *= cB;
#pragma unroll
      for (int d = 0; d < 32; ++d) { accA[d] *= cA; accB[d] *= cB; }
      mxA = nmA; mxB = nmB;
#pragma unroll
      for (int j = 0; j < 8; ++j) {
        scA[j] = __expf(scA[j] - mxA); lA += scA[j];
        scB[j] = __expf(scB[j] - mxB); lB += scB[j];
      }
      // PV
#pragma unroll
      for (int jg = 0; jg < 2; ++jg) {
        const int j0 = grp * 8 + jg * 4;
        float pa0 = scA[jg * 4 + 0], pa1 = scA[jg * 4 + 1];
        float pa2 = scA[jg * 4 + 2], pa3 = scA[jg * 4 + 3];
        float pb0 = scB[jg * 4 + 0], pb1 = scB[jg * 4 + 1];
        float pb2 = scB[jg * 4 + 2], pb3 = scB[jg * 4 + 3];
#pragma unroll
        for (int d = 0; d < 32; ++d) {
          const float4 v = *(const float4*)&pool[sb + (32 + d) * 32 + j0];
          accA[d] = fmaf(pa0, v.x, fmaf(pa1, v.y, fmaf(pa2, v.z, fmaf(pa3, v.w, accA[d]))));
          accB[d] = fmaf(pb0, v.x, fmaf(pb1, v.y, fmaf(pb2, v.z, fmaf(pb3, v.w, accB[d]))));
        }
      }
    }
  }

  // ---- merge 4 key-split partials
  ms_[s][lq] = mxA; ms_[s][64 + lq] = mxB;
  ls_[s][lq] = lA;  ls_[s][64 + lq] = lB;
  __syncthreads();                       // all staging reads done; reuse pool
#pragma unroll
  for (int d = 0; d < 32; ++d) {
    pool[(s * 128 + lq) * 33 + d] = accA[d];
    pool[(s * 128 + 64 + lq) * 33 + d] = accB[d];
  }
  __syncthreads();
  {
    int qq = t & 127, dh = t >> 7;
    float M = fmaxf(fmaxf(ms_[0][qq], ms_[1][qq]), fmaxf(ms_[2][qq], ms_[3][qq]));
    float wg[4], L = 0.f;
#pragma unroll
    for (int ss = 0; ss < 4; ++ss) {
      wg[ss] = __expf(ms_[ss][qq] - M);
      L += ls_[ss][qq] * wg[ss];
    }
    float invL = 1.f / L;
#pragma unroll
    for (int k = 0; k < 16; ++k) {
      int d = dh * 16 + k;
      float o = 0.f;
#pragma unroll
      for (int ss = 0; ss < 4; ++ss) o += pool[(ss * 128 + qq) * 33 + d] * wg[ss];
      O[base + (size_t)(d * 4 + h) * N + q0 + qq] = o * invL;
    }
  }
}

// ---------------------------------------------------------------- BN stats (single pass)
__global__ __launch_bounds__(256) void k_bnstat(const float* __restrict__ h,
                                                float* __restrict__ stat) {
  int c = blockIdx.x, s = blockIdx.y, t = threadIdx.x;
  __shared__ float red[256], red2[256];
  const float* base = h + ((size_t)s * B * 256 + c) * N;
  float sum = 0, sq = 0;
  for (int b = 0; b < B; ++b)
    for (int i = t; i < N; i += 256) {
      float v = base[(size_t)b * 256 * N + i];
      sum += v; sq = fmaf(v, v, sq);
    }
  red[t] = sum; red2[t] = sq; __syncthreads();
  for (int sft = 128; sft > 0; sft >>= 1) {
    if (t < sft) { red[t] += red[t + sft]; red2[t] += red2[t + sft]; }
    __syncthreads();
  }
  if (t == 0) {
    float mean = red[0] / (float)(B * N);
    float var = fmaxf(red2[0] / (float)(B * N) - mean * mean, 0.f);
    stat[(s * 256 + c) * 2 + 0] = mean;
    stat[(s * 256 + c) * 2 + 1] = 1.f / sqrtf(var + 1e-5f);
  }
}

// ---------------------------------------------------------------- mlp2 with fused BN+ReLU + residual
// grid (N/256, 8, 2*B), 16 outputs/thread
__global__ __launch_bounds__(256) void k_mlp2(const float* __restrict__ hb,
                                              const float* __restrict__ stat,
                                              const float* __restrict__ g,
                                              const float* __restrict__ bt,
                                              const float* __restrict__ w,
                                              const float* __restrict__ bias,
                                              const float* __restrict__ res,
                                              float* __restrict__ out) {
  int n = blockIdx.x * 256 + threadIdx.x;
  int o0 = blockIdx.y * 16;
  int z = blockIdx.z;
  int s = z >> 2;
  const float* hp = hb + (size_t)z * 256 * N;
  const float* w0 = w + (size_t)o0 * 256;
  const float* st = stat + (size_t)s * 256 * 2;
  float a[16];
#pragma unroll
  for (int i = 0; i < 16; ++i) a[i] = bias[o0 + i];
#pragma unroll 2
  for (int c = 0; c < 256; ++c) {
    float A = st[c * 2 + 1] * g[c];
    float Bc = fmaf(-st[c * 2 + 0], A, bt[c]);
    float v = fmaxf(fmaf(hp[(size_t)c * N + n], A, Bc), 0.f);
#pragma unroll
    for (int i = 0; i < 16; ++i) a[i] = fmaf(w0[i * 256 + c], v, a[i]);
  }
  size_t ob = ((size_t)z * D + o0) * N + n;
#pragma unroll
  for (int i = 0; i < 16; ++i) out[ob + (size_t)i * N] = a[i] + res[ob + (size_t)i * N];
}

// ---------------------------------------------------------------- pairwise dist (8-m tile)
__global__ __launch_bounds__(256) void k_dist(const float* __restrict__ d0,
                                              const float* __restrict__ d1,
                                              float* __restrict__ la) {
  __shared__ float xm[8][128];
  __shared__ float n0s[8];
  int m0 = blockIdx.x * 8, b = blockIdx.y, t = threadIdx.x;
  const float* p0 = d0 + (size_t)b * D * N;
  const float* p1 = d1 + (size_t)b * D * N;
  for (int i = t; i < 8 * 128; i += 256) {
    int mm = i >> 7, d = i & 127;
    xm[mm][d] = p0[(size_t)d * N + m0 + mm];
  }
  __syncthreads();
  if (t < 8) {
    float s = 0;
    for (int d = 0; d < 128; ++d) s += xm[t][d] * xm[t][d];
    n0s[t] = s;
  }
  __syncthreads();
  float dot[8][4] = {{0}};
  float n1[4] = {0, 0, 0, 0};
  for (int d = 0; d < 128; ++d) {
    float v[4];
#pragma unroll
    for (int u = 0; u < 4; ++u) {
      v[u] = p1[(size_t)d * N + t + u * 256];
      n1[u] = fmaf(v[u], v[u], n1[u]);
    }
#pragma unroll
    for (int mm = 0; mm < 8; ++mm) {
      float x = xm[mm][d];
#pragma unroll
      for (int u = 0; u < 4; ++u) dot[mm][u] = fmaf(x, v[u], dot[mm][u]);
    }
  }
  for (int mm = 0; mm < 8; ++mm) {
    float* row = la + ((size_t)b * N + m0 + mm) * N;
#pragma unroll
    for (int u = 0; u < 4; ++u) {
      float dist2 = fmaxf(n0s[mm] + n1[u] - 2.f * dot[mm][u], 1e-30f);
      row[t + u * 256] = -sqrtf(dist2);
    }
  }
}

// ---------------------------------------------------------------- sinkhorn row (+ pending col sub)
__global__ __launch_bounds__(256) void k_row_lse(float* __restrict__ la,
                                                 const float* __restrict__ colse) {
  __shared__ float red[256];
  int t = threadIdx.x;
  int bm = blockIdx.x;              // over B*N
  int b = bm >> 10;
  float* row = la + (size_t)bm * N;
  float v0 = row[t], v1 = row[t + 256], v2 = row[t + 512], v3 = row[t + 768];
  if (colse) {
    const float* cl = colse + (size_t)b * N;
    v0 -= cl[t]; v1 -= cl[t + 256]; v2 -= cl[t + 512]; v3 -= cl[t + 768];
  }
  float mx = fmaxf(fmaxf(v0, v1), fmaxf(v2, v3));
  red[t] = mx; __syncthreads();
  for (int s = 128; s > 0; s >>= 1) {
    if (t < s) red[t] = fmaxf(red[t], red[t + s]);
    __syncthreads();
  }
  mx = red[0]; __syncthreads();
  float se = __expf(v0 - mx) + __expf(v1 - mx) + __expf(v2 - mx) + __expf(v3 - mx);
  red[t] = se; __syncthreads();
  for (int s = 128; s > 0; s >>= 1) {
    if (t < s) red[t] += red[t + s];
    __syncthreads();
  }
  float lse = mx + __logf(red[0]);
  row[t] = v0 - lse; row[t + 256] = v1 - lse;
  row[t + 512] = v2 - lse; row[t + 768] = v3 - lse;
}

// ---------------------------------------------------------------- sinkhorn col (16 partials)
__global__ __launch_bounds__(256) void k_col_part(const float* __restrict__ la,
                                                  float* __restrict__ pmax,
                                                  float* __restrict__ psum) {
  int t = threadIdx.x;
  int n = blockIdx.x * 256 + t;
  int p = blockIdx.y, b = blockIdx.z;
  const float* base = la + ((size_t)b * N + p * 64) * N + n;
  float mx = -1e30f, s = 0;
  for (int m = 0; m < 64; ++m) {
    float v = base[(size_t)m * N];
    if (v > mx) { s = s * __expf(mx - v) + 1.f; mx = v; }
    else s += __expf(v - mx);
  }
  pmax[((size_t)b * 16 + p) * N + n] = mx;
  psum[((size_t)b * 16 + p) * N + n] = s;
}

__global__ __launch_bounds__(256) void k_col_fin(const float* __restrict__ pmax,
                                                 const float* __restrict__ psum,
                                                 float* __restrict__ lse) {
  int i = blockIdx.x * 256 + threadIdx.x;  // over B*N
  int b = i / N, n = i % N;
  float mx = -1e30f;
#pragma unroll
  for (int p = 0; p < 16; ++p) mx = fmaxf(mx, pmax[((size_t)b * 16 + p) * N + n]);
  float s = 0;
#pragma unroll
  for (int p = 0; p < 16; ++p)
    s += psum[((size_t)b * 16 + p) * N + n] * __expf(pmax[((size_t)b * 16 + p) * N + n] - mx);
  lse[i] = mx + __logf(s);
}

// ---------------------------------------------------------------- rodrigues + transform
__global__ __launch_bounds__(256) void k_rod(const float* __restrict__ pose,
                                             const float* __restrict__ p3d,
                                             float* __restrict__ p3dt) {
  int b = blockIdx.y;
  int n = blockIdx.x * 256 + threadIdx.x;
  const float* aa = pose + b * 6;
  float ax = aa[0], ay = aa[1], az = aa[2];
  float th = fmaxf(sqrtf(ax * ax + ay * ay + az * az), 1e-8f);
  float rx = ax / th, ry = ay / th, rz = az / th;
  float c = cosf(th), s = sinf(th), oc = 1.f - c;
  float R00 = c + oc * rx * rx,      R01 = oc * rx * ry - s * rz, R02 = oc * rx * rz + s * ry;
  float R10 = oc * ry * rx + s * rz, R11 = c + oc * ry * ry,      R12 = oc * ry * rz - s * rx;
  float R20 = oc * rz * rx - s * ry, R21 = oc * rz * ry + s * rx, R22 = c + oc * rz * rz;
  const float* p = p3d + ((size_t)b * N + n) * 3;
  float x = p[0], y = p[1], z = p[2];
  float X = R00 * x + R01 * y + R02 * z + aa[3];
  float Y = R10 * x + R11 * y + R12 * z + aa[4];
  float Z = R20 * x + R21 * y + R22 * z + aa[5];
  float inr = 1.f / sqrtf(X * X + Y * Y + Z * Z);
  float* o = p3dt + ((size_t)b * N + n) * 3;
  o[0] = X * inr; o[1] = Y * inr; o[2] = Z * inr;
}

// ---------------------------------------------------------------- final error
__global__ __launch_bounds__(256) void k_err(const float* __restrict__ la,
                                             const float* __restrict__ colse,
                                             const float* __restrict__ f2,
                                             const float* __restrict__ p3dt,
                                             float* __restrict__ rowsum) {
  __shared__ float red[256];
  int m = blockIdx.x, b = blockIdx.y, t = threadIdx.x;
  const float* row = la + ((size_t)b * N + m) * N;
  const float* cl = colse + (size_t)b * N;
  const float* f = f2 + ((size_t)b * N + m) * 3;
  float fx = f[0], fy = f[1], fz = f[2];
  float s = 0;
  for (int n = t; n < N; n += 256) {
    const float* pp = p3dt + ((size_t)b * N + n) * 3;
    float dot = fx * pp[0] + fy * pp[1] + fz * pp[2];
    s += __expf(row[n] - cl[n]) * (1.f - dot);
  }
  red[t] = s; __syncthreads();
  for (int sft = 128; sft > 0; sft >>= 1) {
    if (t < sft) red[t] += red[t + sft];
    __syncthreads();
  }
  if (t == 0) rowsum[(size_t)b * N + m] = red[0];
}

__global__ __launch_bounds__(256) void k_err_fin(const float* __restrict__ rowsum,
                                                 float* __restrict__ out) {
  __shared__ float red[256];
  int b = blockIdx.x, t = threadIdx.x;
  float s = 0;
  for (int i = t; i < N; i += 256) s += rowsum[(size_t)b * N + i];
  red[t] = s; __syncthreads();
  for (int sft = 128; sft > 0; sft >>= 1) {
    if (t < sft) red[t] += red[t + sft];
    __syncthreads();
  }
  if (t == 0) out[b] = red[0];
}

// ================================================================= host
extern "C" void kernel_launch(void* const* d_in, const int* in_sizes, int n_in,
                              void* d_out, int out_size, void* d_ws, size_t ws_size,
                              hipStream_t stream) {
  const float* p2d     = (const float*)d_in[0];
  const float* p3d     = (const float*)d_in[1];
  const float* pose    = (const float*)d_in[2];
  const float* enc2d_w = (const float*)d_in[3];
  const float* enc2d_b = (const float*)d_in[4];
  const float* enc3d_w = (const float*)d_in[5];
  const float* enc3d_b = (const float*)d_in[6];
  const float* proj_w  = (const float*)d_in[7];
  const float* proj_b  = (const float*)d_in[8];
  const float* merge_w = (const float*)d_in[9];
  const float* merge_b = (const float*)d_in[10];
  const float* mlp1_w  = (const float*)d_in[11];
  const float* mlp1_b  = (const float*)d_in[12];
  const float* bn_g    = (const float*)d_in[13];
  const float* bn_b    = (const float*)d_in[14];
  const float* mlp2_w  = (const float*)d_in[15];
  const float* mlp2_b  = (const float*)d_in[16];

  float* W = (float*)d_ws;
  size_t off = 0;
  auto alloc = [&](size_t nelem) { float* p = W + off; off += nelem; return p; };
  const size_t SET = (size_t)B * D * N;
  float* f2    = alloc((size_t)B * N * 3);
  float* p3dt  = alloc((size_t)B * N * 3);
  float* descA = alloc(2 * SET);
  float* descB = alloc(2 * SET);
  float* Qb    = alloc(2 * SET);
  float* Kb    = alloc(2 * SET);
  float* Vb    = alloc(2 * SET);
  float* attnb = alloc(2 * SET);
  float* msgb  = alloc(2 * SET);
  float* hb    = alloc((size_t)2 * B * 256 * N);
  float* stat  = alloc(2 * 256 * 2);
  float* la    = alloc((size_t)B * N * N);
  float* pmax  = alloc((size_t)B * 16 * N);
  float* psum  = alloc((size_t)B * 16 * N);
  float* lseb  = alloc((size_t)B * N);
  float* rowsum= alloc((size_t)B * N);
  (void)ws_size; (void)in_sizes; (void)n_in; (void)out_size;

  auto conv = [&](const float* in0, const float* in1, const float* cat0,
                  const float* cat1, const float* w, const float* bias,
                  const float* res, float* out, int Cin, int catOff,
                  size_t in_bstr, size_t cat_bstr, int Cout) {
    dim3 g(N / 256, Cout / 16, 2 * B);
    k_conv<<<g, 256, 0, stream>>>(in0, in1, cat0, cat1, w, bias, res, out,
                                  Cin, catOff, in_bstr, cat_bstr, Cout);
  };

  k_norm2d<<<(B * N) / 256, 256, 0, stream>>>(p2d, f2);
  k_encode<<<dim3(N, B), 256, 0, stream>>>(f2, enc2d_w, enc2d_b, descA);
  k_encode<<<dim3(N, B), 256, 0, stream>>>(p3d, enc3d_w, enc3d_b, descA + SET);

  float* dc = descA;
  float* dn = descB;
  for (int i = 0; i < 6; ++i) {
    int cross = (i & 1);
    const float* pw = proj_w + (size_t)i * 3 * D * D;
    const float* pb = proj_b + (size_t)i * 3 * D;
    k_qkv<<<dim3(N / 256, 24, 2 * B), 256, 0, stream>>>(dc, pw, pb, Qb, Kb, Vb, cross);
    k_attn<<<dim3(N / 128, NH, 2 * B), 256, 0, stream>>>(Qb, Kb, Vb, attnb);
    conv(attnb, attnb + SET, nullptr, nullptr, merge_w + (size_t)i * D * D,
         merge_b + (size_t)i * D, nullptr, msgb, D, D, (size_t)D * N, 0, D);
    conv(dc, dc + SET, msgb, msgb + SET, mlp1_w + (size_t)i * 256 * 256,
         mlp1_b + (size_t)i * 256, nullptr, hb, 256, 128, (size_t)D * N,
         (size_t)D * N, 256);
    k_bnstat<<<dim3(256, 2), 256, 0, stream>>>(hb, stat);
    k_mlp2<<<dim3(N / 256, 8, 2 * B), 256, 0, stream>>>(
        hb, stat, bn_g + (size_t)i * 256, bn_b + (size_t)i * 256,
        mlp2_w + (size_t)i * D * 256, mlp2_b + (size_t)i * D, dc, dn);
    float* tmp = dc; dc = dn; dn = tmp;
  }

  k_dist<<<dim3(N / 8, B), 256, 0, stream>>>(dc, dc + SET, la);
  for (int it = 0; it < 10; ++it) {
    k_row_lse<<<B * N, 256, 0, stream>>>(la, it == 0 ? nullptr : lseb);
    k_col_part<<<dim3(N / 256, 16, B), 256, 0, stream>>>(la, pmax, psum);
    k_col_fin<<<(B * N) / 256, 256, 0, stream>>>(pmax, psum, lseb);
  }
  k_rod<<<dim3(N / 256, B), 256, 0, stream>>>(pose, p3d, p3dt);
  k_err<<<dim3(N, B), 256, 0, stream>>>(la, lseb, f2, p3dt, rowsum);
  k_err_fin<<<B, 256, 0, stream>>>(rowsum, (float*)d_out);
}

// Round 8
// 2088.342 us; speedup vs baseline: 2.1681x; 1.0608x over previous
//
#include <hip/hip_runtime.h>
#include <hip/hip_bf16.h>

constexpr int B   = 4;
constexpr int N   = 1024;
constexpr int D   = 128;
constexpr int KNN = 10;
constexpr int NH  = 4;

// ---------------------------------------------------------------- norm p2d
__global__ __launch_bounds__(256) void k_norm2d(const float* __restrict__ p2d,
                                                float* __restrict__ f2) {
  int i = blockIdx.x * 256 + threadIdx.x;  // over B*N
  const float* p = p2d + (size_t)i * 3;
  float x = p[0], y = p[1], z = p[2];
  float inr = 1.f / sqrtf(x * x + y * y + z * z);
  float* o = f2 + (size_t)i * 3;
  o[0] = x * inr; o[1] = y * inr; o[2] = z * inr;
}

// ---------------------------------------------------------------- KNN encode
__global__ __launch_bounds__(256) void k_encode(const float* __restrict__ pts,
                                                const float* __restrict__ w,
                                                const float* __restrict__ bias,
                                                float* __restrict__ desc) {
  __shared__ float P[N][3];
  __shared__ float xx[N];
  __shared__ float dist[N];
  __shared__ float rv[256];
  __shared__ int   ri[256];
  __shared__ float feat[6];
  __shared__ int   nidx[KNN];
  int t = threadIdx.x;
  int n = blockIdx.x, b = blockIdx.y;
  const float* pb = pts + (size_t)b * N * 3;
  for (int i = t; i < N; i += 256) {
    float x = pb[i * 3 + 0], y = pb[i * 3 + 1], z = pb[i * 3 + 2];
    P[i][0] = x; P[i][1] = y; P[i][2] = z;
    xx[i] = x * x + y * y + z * z;
  }
  __syncthreads();
  float cx = P[n][0], cy = P[n][1], cz = P[n][2], cxx = xx[n];
  for (int i = t; i < N; i += 256) {
    float ip = cx * P[i][0] + cy * P[i][1] + cz * P[i][2];
    dist[i] = 2.f * ip - cxx - xx[i];
  }
  __syncthreads();
  for (int kk = 0; kk < KNN; ++kk) {
    float bv = -3.0e38f; int bi = N;
    for (int i = t; i < N; i += 256) {
      float v = dist[i];
      if (v > bv) { bv = v; bi = i; }
    }
    rv[t] = bv; ri[t] = bi;
    __syncthreads();
    for (int s = 128; s > 0; s >>= 1) {
      if (t < s) {
        float v2 = rv[t + s]; int i2 = ri[t + s];
        if (v2 > rv[t] || (v2 == rv[t] && i2 < ri[t])) { rv[t] = v2; ri[t] = i2; }
      }
      __syncthreads();
    }
    if (t == 0) { nidx[kk] = ri[0]; dist[ri[0]] = -3.0e38f; }
    __syncthreads();
  }
  if (t == 0) {
    float sx = 0, sy = 0, sz = 0;
    for (int kk = 0; kk < KNN; ++kk) {
      int i = nidx[kk];
      sx += P[i][0]; sy += P[i][1]; sz += P[i][2];
    }
    const float invk = 1.f / KNN;
    feat[0] = sx * invk - cx; feat[1] = sy * invk - cy; feat[2] = sz * invk - cz;
    feat[3] = cx; feat[4] = cy; feat[5] = cz;
  }
  __syncthreads();
  if (t < D) {
    const float* wr = w + t * 6;
    float a = bias[t];
#pragma unroll
    for (int j = 0; j < 6; ++j) a += wr[j] * feat[j];
    desc[((size_t)b * D + t) * N + n] = a;
  }
}

// ---------------------------------------------------------------- fused QKV conv (16-o groups)
// grid (N/256, 24, 2*B). unroll 8: 8 independent input loads in flight
// (inner loop is latency-bound at 2 blocks/CU, not VALU-bound).
__global__ __launch_bounds__(256) void k_qkv(const float* __restrict__ desc,
                                             const float* __restrict__ pw,
                                             const float* __restrict__ pb,
                                             float* __restrict__ Qb,
                                             float* __restrict__ Kb,
                                             float* __restrict__ Vb,
                                             int cross) {
  int n = blockIdx.x * 256 + threadIdx.x;
  int gy = blockIdx.y;
  int seg = gy >> 3;            // 0=Q, 1=K, 2=V
  int o0 = (gy & 7) * 16;
  int z = blockIdx.z;           // s*B + b
  int s = z >> 2, b = z & 3;
  int si = (seg == 0) ? s : (cross ? 1 - s : s);
  const float* ip = desc + ((size_t)si * B + b) * (size_t)(D * N);
  const float* w0 = pw + (size_t)seg * D * D + (size_t)o0 * D;
  const float* bp = pb + seg * D + o0;
  float a[16];
#pragma unroll
  for (int i = 0; i < 16; ++i) a[i] = bp[i];
#pragma unroll 8
  for (int c = 0; c < D; ++c) {
    float v = ip[(size_t)c * N + n];
#pragma unroll
    for (int i = 0; i < 16; ++i) a[i] = fmaf(w0[i * D + c], v, a[i]);
  }
  float* out = (seg == 0) ? Qb : (seg == 1) ? Kb : Vb;
  size_t ob = ((size_t)z * D + o0) * N + n;
#pragma unroll
  for (int i = 0; i < 16; ++i) out[ob + (size_t)i * N] = a[i];
}

// ---------------------------------------------------------------- generic conv1 (16-o unroll)
// grid (N/256, Cout/16, 2*B)
__global__ __launch_bounds__(256) void k_conv(const float* __restrict__ in0,
                                              const float* __restrict__ in1,
                                              const float* __restrict__ cat0,
                                              const float* __restrict__ cat1,
                                              const float* __restrict__ w,
                                              const float* __restrict__ bias,
                                              const float* __restrict__ res,
                                              float* __restrict__ out,
                                              int Cin, int catOff,
                                              size_t in_bstr, size_t cat_bstr,
                                              int Cout) {
  int n = blockIdx.x * 256 + threadIdx.x;
  int o0 = blockIdx.y * 16;
  int z = blockIdx.z;           // s*B + b
  int s = z >> 2, b = z & 3;
  const float* ip = (s ? in1 : in0) + (size_t)b * in_bstr;
  const float* w0 = w + (size_t)o0 * Cin;
  float a[16];
#pragma unroll
  for (int i = 0; i < 16; ++i) a[i] = bias[o0 + i];
#pragma unroll 8
  for (int c = 0; c < catOff; ++c) {
    float v = ip[(size_t)c * N + n];
#pragma unroll
    for (int i = 0; i < 16; ++i) a[i] = fmaf(w0[i * Cin + c], v, a[i]);
  }
  if (cat0) {
    const float* cp = (s ? cat1 : cat0) + (size_t)b * cat_bstr;
#pragma unroll 8
    for (int c = catOff; c < Cin; ++c) {
      float v = cp[(size_t)(c - catOff) * N + n];
#pragma unroll
      for (int i = 0; i < 16; ++i) a[i] = fmaf(w0[i * Cin + c], v, a[i]);
    }
  }
  size_t ob = ((size_t)z * Cout + o0) * N + n;
  if (res) {
#pragma unroll
    for (int i = 0; i < 16; ++i) a[i] += res[ob + (size_t)i * N];
  }
#pragma unroll
  for (int i = 0; i < 16; ++i) out[ob + (size_t)i * N] = a[i];
}

// ---------------------------------------------------------------- attention v5 (116us verified)
// grid (N/128, NH, 2*B), 256 thr = 4 waves. Wave s owns keys [s*256,(s+1)*256).
// Each lane owns TWO queries. K/V chunks of 32 keys staged per-wave in LDS
// (contiguous float4 writes, broadcast b128 reads feed 8 FMAs); no barriers in
// the K-loop. R6: direct global loads 4.5x slower. R4: no min-waves bound.
__global__ __launch_bounds__(256) void k_attn(const float* __restrict__ Q,
                                              const float* __restrict__ Kt,
                                              const float* __restrict__ Vt,
                                              float* __restrict__ O) {
  __shared__ float pool[16896];
  __shared__ float ms_[4][128], ls_[4][128];
  const int t  = threadIdx.x;
  const int lq = t & 63, s = t >> 6;
  const int q0 = blockIdx.x * 128;
  const int h  = blockIdx.y;
  const int z  = blockIdx.z;
  const size_t base = (size_t)z * (size_t)(D * N);
  const float* Kb = Kt + base;
  const float* Vb = Vt + base;
  const int sb    = s * 2048;
  const int wrow  = lq >> 3;
  const int wslot = (lq & 7) * 4;

  const float scale = 0.17677669529663687f;
  float qA[32], qB[32], accA[32], accB[32];
#pragma unroll
  for (int d = 0; d < 32; ++d) {
    qA[d] = Q[base + (size_t)(d * 4 + h) * N + q0 + lq] * scale;
    qB[d] = Q[base + (size_t)(d * 4 + h) * N + q0 + 64 + lq] * scale;
    accA[d] = 0.f; accB[d] = 0.f;
  }
  float mxA = -1e30f, mxB = -1e30f, lA = 0.f, lB = 0.f;

  for (int c = 0; c < 8; ++c) {
    const int k0 = s * 256 + c * 32;
#pragma unroll
    for (int it = 0; it < 8; ++it) {
      int row = it * 8 + wrow;
      const float* src = (row < 32) ? (Kb + (size_t)(row * 4 + h) * N)
                                    : (Vb + (size_t)((row - 32) * 4 + h) * N);
      *(float4*)&pool[sb + row * 32 + wslot] = *(const float4*)(src + k0 + wslot);
    }
#pragma unroll
    for (int grp = 0; grp < 4; ++grp) {
      float scA[8], scB[8];
#pragma unroll
      for (int jg = 0; jg < 2; ++jg) {
        const int j0 = grp * 8 + jg * 4;
        float a0 = 0, a1 = 0, a2 = 0, a3 = 0, b0 = 0, b1 = 0, b2 = 0, b3 = 0;
#pragma unroll
        for (int d = 0; d < 32; ++d) {
          const float4 kv = *(const float4*)&pool[sb + d * 32 + j0];
          a0 = fmaf(qA[d], kv.x, a0); a1 = fmaf(qA[d], kv.y, a1);
          a2 = fmaf(qA[d], kv.z, a2); a3 = fmaf(qA[d], kv.w, a3);
          b0 = fmaf(qB[d], kv.x, b0); b1 = fmaf(qB[d], kv.y, b1);
          b2 = fmaf(qB[d], kv.z, b2); b3 = fmaf(qB[d], kv.w, b3);
        }
        scA[jg * 4 + 0] = a0; scA[jg * 4 + 1] = a1;
        scA[jg * 4 + 2] = a2; scA[jg * 4 + 3] = a3;
        scB[jg * 4 + 0] = b0; scB[jg * 4 + 1] = b1;
        scB[jg * 4 + 2] = b2; scB[jg * 4 + 3] = b3;
      }
      float hA = scA[0], hB = scB[0];
#pragma unroll
      for (int j = 1; j < 8; ++j) { hA = fmaxf(hA, scA[j]); hB = fmaxf(hB, scB[j]); }
      float nmA = fmaxf(mxA, hA), nmB = fmaxf(mxB, hB);
      float cA = __expf(mxA - nmA), cB = __expf(mxB - nmB);
      lA *= cA; lB *= cB;
#pragma unroll
      for (int d = 0; d < 32; ++d) { accA[d] *= cA; accB[d] *= cB; }
      mxA = nmA; mxB = nmB;
#pragma unroll
      for (int j = 0; j < 8; ++j) {
        scA[j] = __expf(scA[j] - mxA); lA += scA[j];
        scB[j] = __expf(scB[j] - mxB); lB += scB[j];
      }
#pragma unroll
      for (int jg = 0; jg < 2; ++jg) {
        const int j0 = grp * 8 + jg * 4;
        float pa0 = scA[jg * 4 + 0], pa1 = scA[jg * 4 + 1];
        float pa2 = scA[jg * 4 + 2], pa3 = scA[jg * 4 + 3];
        float pb0 = scB[jg * 4 + 0], pb1 = scB[jg * 4 + 1];
        float pb2 = scB[jg * 4 + 2], pb3 = scB[jg * 4 + 3];
#pragma unroll
        for (int d = 0; d < 32; ++d) {
          const float4 v = *(const float4*)&pool[sb + (32 + d) * 32 + j0];
          accA[d] = fmaf(pa0, v.x, fmaf(pa1, v.y, fmaf(pa2, v.z, fmaf(pa3, v.w, accA[d]))));
          accB[d] = fmaf(pb0, v.x, fmaf(pb1, v.y, fmaf(pb2, v.z, fmaf(pb3, v.w, accB[d]))));
        }
      }
    }
  }

  ms_[s][lq] = mxA; ms_[s][64 + lq] = mxB;
  ls_[s][lq] = lA;  ls_[s][64 + lq] = lB;
  __syncthreads();
#pragma unroll
  for (int d = 0; d < 32; ++d) {
    pool[(s * 128 + lq) * 33 + d] = accA[d];
    pool[(s * 128 + 64 + lq) * 33 + d] = accB[d];
  }
  __syncthreads();
  {
    int qq = t & 127, dh = t >> 7;
    float M = fmaxf(fmaxf(ms_[0][qq], ms_[1][qq]), fmaxf(ms_[2][qq], ms_[3][qq]));
    float wg[4], L = 0.f;
#pragma unroll
    for (int ss = 0; ss < 4; ++ss) {
      wg[ss] = __expf(ms_[ss][qq] - M);
      L += ls_[ss][qq] * wg[ss];
    }
    float invL = 1.f / L;
#pragma unroll
    for (int k = 0; k < 16; ++k) {
      int d = dh * 16 + k;
      float o = 0.f;
#pragma unroll
      for (int ss = 0; ss < 4; ++ss) o += pool[(ss * 128 + qq) * 33 + d] * wg[ss];
      O[base + (size_t)(d * 4 + h) * N + q0 + qq] = o * invL;
    }
  }
}

// ---------------------------------------------------------------- BN stats (single pass)
__global__ __launch_bounds__(256) void k_bnstat(const float* __restrict__ h,
                                                float* __restrict__ stat) {
  int c = blockIdx.x, s = blockIdx.y, t = threadIdx.x;
  __shared__ float red[256], red2[256];
  const float* base = h + ((size_t)s * B * 256 + c) * N;
  float sum = 0, sq = 0;
  for (int b = 0; b < B; ++b)
    for (int i = t; i < N; i += 256) {
      float v = base[(size_t)b * 256 * N + i];
      sum += v; sq = fmaf(v, v, sq);
    }
  red[t] = sum; red2[t] = sq; __syncthreads();
  for (int sft = 128; sft > 0; sft >>= 1) {
    if (t < sft) { red[t] += red[t + sft]; red2[t] += red2[t + sft]; }
    __syncthreads();
  }
  if (t == 0) {
    float mean = red[0] / (float)(B * N);
    float var = fmaxf(red2[0] / (float)(B * N) - mean * mean, 0.f);
    stat[(s * 256 + c) * 2 + 0] = mean;
    stat[(s * 256 + c) * 2 + 1] = 1.f / sqrtf(var + 1e-5f);
  }
}

// ---------------------------------------------------------------- mlp2: fused BN+ReLU+residual
// grid (N/256, 8, 2*B). BN coefs staged in LDS once per block; unroll 8.
__global__ __launch_bounds__(256) void k_mlp2(const float* __restrict__ hb,
                                              const float* __restrict__ stat,
                                              const float* __restrict__ g,
                                              const float* __restrict__ bt,
                                              const float* __restrict__ w,
                                              const float* __restrict__ bias,
                                              const float* __restrict__ res,
                                              float* __restrict__ out) {
  __shared__ float As[256], Bs[256];
  int t = threadIdx.x;
  int n = blockIdx.x * 256 + t;
  int o0 = blockIdx.y * 16;
  int z = blockIdx.z;
  int s = z >> 2;
  const float* st = stat + (size_t)s * 256 * 2;
  {
    float A = st[t * 2 + 1] * g[t];
    As[t] = A;
    Bs[t] = fmaf(-st[t * 2 + 0], A, bt[t]);
  }
  __syncthreads();
  const float* hp = hb + (size_t)z * 256 * N;
  const float* w0 = w + (size_t)o0 * 256;
  float a[16];
#pragma unroll
  for (int i = 0; i < 16; ++i) a[i] = bias[o0 + i];
#pragma unroll 8
  for (int c = 0; c < 256; ++c) {
    float v = fmaxf(fmaf(hp[(size_t)c * N + n], As[c], Bs[c]), 0.f);
#pragma unroll
    for (int i = 0; i < 16; ++i) a[i] = fmaf(w0[i * 256 + c], v, a[i]);
  }
  size_t ob = ((size_t)z * D + o0) * N + n;
#pragma unroll
  for (int i = 0; i < 16; ++i) out[ob + (size_t)i * N] = a[i] + res[ob + (size_t)i * N];
}

// ---------------------------------------------------------------- pairwise dist (8-m tile)
// writes logits0 = -M (read-only afterwards: sinkhorn runs in offset form)
__global__ __launch_bounds__(256) void k_dist(const float* __restrict__ d0,
                                              const float* __restrict__ d1,
                                              float* __restrict__ la) {
  __shared__ float xm[8][128];
  __shared__ float n0s[8];
  int m0 = blockIdx.x * 8, b = blockIdx.y, t = threadIdx.x;
  const float* p0 = d0 + (size_t)b * D * N;
  const float* p1 = d1 + (size_t)b * D * N;
  for (int i = t; i < 8 * 128; i += 256) {
    int mm = i >> 7, d = i & 127;
    xm[mm][d] = p0[(size_t)d * N + m0 + mm];
  }
  __syncthreads();
  if (t < 8) {
    float s = 0;
    for (int d = 0; d < 128; ++d) s += xm[t][d] * xm[t][d];
    n0s[t] = s;
  }
  __syncthreads();
  float dot[8][4] = {{0}};
  float n1[4] = {0, 0, 0, 0};
  for (int d = 0; d < 128; ++d) {
    float v[4];
#pragma unroll
    for (int u = 0; u < 4; ++u) {
      v[u] = p1[(size_t)d * N + t + u * 256];
      n1[u] = fmaf(v[u], v[u], n1[u]);
    }
#pragma unroll
    for (int mm = 0; mm < 8; ++mm) {
      float x = xm[mm][d];
#pragma unroll
      for (int u = 0; u < 4; ++u) dot[mm][u] = fmaf(x, v[u], dot[mm][u]);
    }
  }
  for (int mm = 0; mm < 8; ++mm) {
    float* row = la + ((size_t)b * N + m0 + mm) * N;
#pragma unroll
    for (int u = 0; u < 4; ++u) {
      float dist2 = fmaxf(n0s[mm] + n1[u] - 2.f * dot[mm][u], 1e-30f);
      row[t + u * 256] = -sqrtf(dist2);
    }
  }
}

// ---------------------------------------------------------------- sinkhorn offset form
// r[m] = LSE_n(l0[m,n] - c[n]); c[n] = LSE_m(l0[m,n] - r[m]). l0 never written.
__global__ __launch_bounds__(256) void k_row_r(const float* __restrict__ l0,
                                               const float* __restrict__ cvec,
                                               float* __restrict__ r,
                                               int useC) {
  __shared__ float red[256];
  int t = threadIdx.x;
  int bm = blockIdx.x;              // over B*N
  int b = bm >> 10;
  const float* row = l0 + (size_t)bm * N;
  float v0 = row[t], v1 = row[t + 256], v2 = row[t + 512], v3 = row[t + 768];
  if (useC) {
    const float* cl = cvec + (size_t)b * N;
    v0 -= cl[t]; v1 -= cl[t + 256]; v2 -= cl[t + 512]; v3 -= cl[t + 768];
  }
  float mx = fmaxf(fmaxf(v0, v1), fmaxf(v2, v3));
  red[t] = mx; __syncthreads();
  for (int s = 128; s > 0; s >>= 1) {
    if (t < s) red[t] = fmaxf(red[t], red[t + s]);
    __syncthreads();
  }
  mx = red[0]; __syncthreads();
  float se = __expf(v0 - mx) + __expf(v1 - mx) + __expf(v2 - mx) + __expf(v3 - mx);
  red[t] = se; __syncthreads();
  for (int s = 128; s > 0; s >>= 1) {
    if (t < s) red[t] += red[t + s];
    __syncthreads();
  }
  if (t == 0) r[bm] = mx + __logf(red[0]);
}

__global__ __launch_bounds__(256) void k_col_part(const float* __restrict__ l0,
                                                  const float* __restrict__ r,
                                                  float* __restrict__ pmax,
                                                  float* __restrict__ psum) {
  int t = threadIdx.x;
  int n = blockIdx.x * 256 + t;
  int p = blockIdx.y, b = blockIdx.z;
  const float* base = l0 + ((size_t)b * N + p * 64) * N + n;
  const float* rr = r + (size_t)b * N + p * 64;
  float mx = -1e30f, s = 0;
  for (int m = 0; m < 64; ++m) {
    float v = base[(size_t)m * N] - rr[m];
    if (v > mx) { s = s * __expf(mx - v) + 1.f; mx = v; }
    else s += __expf(v - mx);
  }
  pmax[((size_t)b * 16 + p) * N + n] = mx;
  psum[((size_t)b * 16 + p) * N + n] = s;
}

__global__ __launch_bounds__(256) void k_col_fin(const float* __restrict__ pmax,
                                                 const float* __restrict__ psum,
                                                 float* __restrict__ cvec) {
  int i = blockIdx.x * 256 + threadIdx.x;  // over B*N
  int b = i / N, n = i % N;
  float mx = -1e30f;
#pragma unroll
  for (int p = 0; p < 16; ++p) mx = fmaxf(mx, pmax[((size_t)b * 16 + p) * N + n]);
  float s = 0;
#pragma unroll
  for (int p = 0; p < 16; ++p)
    s += psum[((size_t)b * 16 + p) * N + n] * __expf(pmax[((size_t)b * 16 + p) * N + n] - mx);
  cvec[i] = mx + __logf(s);
}

// ---------------------------------------------------------------- rodrigues + transform
__global__ __launch_bounds__(256) void k_rod(const float* __restrict__ pose,
                                             const float* __restrict__ p3d,
                                             float* __restrict__ p3dt) {
  int b = blockIdx.y;
  int n = blockIdx.x * 256 + threadIdx.x;
  const float* aa = pose + b * 6;
  float ax = aa[0], ay = aa[1], az = aa[2];
  float th = fmaxf(sqrtf(ax * ax + ay * ay + az * az), 1e-8f);
  float rx = ax / th, ry = ay / th, rz = az / th;
  float c = cosf(th), s = sinf(th), oc = 1.f - c;
  float R00 = c + oc * rx * rx,      R01 = oc * rx * ry - s * rz, R02 = oc * rx * rz + s * ry;
  float R10 = oc * ry * rx + s * rz, R11 = c + oc * ry * ry,      R12 = oc * ry * rz - s * rx;
  float R20 = oc * rz * rx - s * ry, R21 = oc * rz * ry + s * rx, R22 = c + oc * rz * rz;
  const float* p = p3d + ((size_t)b * N + n) * 3;
  float x = p[0], y = p[1], z = p[2];
  float X = R00 * x + R01 * y + R02 * z + aa[3];
  float Y = R10 * x + R11 * y + R12 * z + aa[4];
  float Z = R20 * x + R21 * y + R22 * z + aa[5];
  float inr = 1.f / sqrtf(X * X + Y * Y + Z * Z);
  float* o = p3dt + ((size_t)b * N + n) * 3;
  o[0] = X * inr; o[1] = Y * inr; o[2] = Z * inr;
}

// ---------------------------------------------------------------- final error (applies r,c offsets)
__global__ __launch_bounds__(256) void k_err(const float* __restrict__ l0,
                                             const float* __restrict__ r,
                                             const float* __restrict__ cvec,
                                             const float* __restrict__ f2,
                                             const float* __restrict__ p3dt,
                                             float* __restrict__ rowsum) {
  __shared__ float red[256];
  int m = blockIdx.x, b = blockIdx.y, t = threadIdx.x;
  const float* row = l0 + ((size_t)b * N + m) * N;
  const float* cl = cvec + (size_t)b * N;
  const float rm = r[(size_t)b * N + m];
  const float* f = f2 + ((size_t)b * N + m) * 3;
  float fx = f[0], fy = f[1], fz = f[2];
  float s = 0;
  for (int n = t; n < N; n += 256) {
    const float* pp = p3dt + ((size_t)b * N + n) * 3;
    float dot = fx * pp[0] + fy * pp[1] + fz * pp[2];
    s += __expf(row[n] - rm - cl[n]) * (1.f - dot);
  }
  red[t] = s; __syncthreads();
  for (int sft = 128; sft > 0; sft >>= 1) {
    if (t < sft) red[t] += red[t + sft];
    __syncthreads();
  }
  if (t == 0) rowsum[(size_t)b * N + m] = red[0];
}

__global__ __launch_bounds__(256) void k_err_fin(const float* __restrict__ rowsum,
                                                 float* __restrict__ out) {
  __shared__ float red[256];
  int b = blockIdx.x, t = threadIdx.x;
  float s = 0;
  for (int i = t; i < N; i += 256) s += rowsum[(size_t)b * N + i];
  red[t] = s; __syncthreads();
  for (int sft = 128; sft > 0; sft >>= 1) {
    if (t < sft) red[t] += red[t + sft];
    __syncthreads();
  }
  if (t == 0) out[b] = red[0];
}

// ================================================================= host
extern "C" void kernel_launch(void* const* d_in, const int* in_sizes, int n_in,
                              void* d_out, int out_size, void* d_ws, size_t ws_size,
                              hipStream_t stream) {
  const float* p2d     = (const float*)d_in[0];
  const float* p3d     = (const float*)d_in[1];
  const float* pose    = (const float*)d_in[2];
  const float* enc2d_w = (const float*)d_in[3];
  const float* enc2d_b = (const float*)d_in[4];
  const float* enc3d_w = (const float*)d_in[5];
  const float* enc3d_b = (const float*)d_in[6];
  const float* proj_w  = (const float*)d_in[7];
  const float* proj_b  = (const float*)d_in[8];
  const float* merge_w = (const float*)d_in[9];
  const float* merge_b = (const float*)d_in[10];
  const float* mlp1_w  = (const float*)d_in[11];
  const float* mlp1_b  = (const float*)d_in[12];
  const float* bn_g    = (const float*)d_in[13];
  const float* bn_b    = (const float*)d_in[14];
  const float* mlp2_w  = (const float*)d_in[15];
  const float* mlp2_b  = (const float*)d_in[16];

  float* W = (float*)d_ws;
  size_t off = 0;
  auto alloc = [&](size_t nelem) { float* p = W + off; off += nelem; return p; };
  const size_t SET = (size_t)B * D * N;
  float* f2    = alloc((size_t)B * N * 3);
  float* p3dt  = alloc((size_t)B * N * 3);
  float* descA = alloc(2 * SET);
  float* descB = alloc(2 * SET);
  float* Qb    = alloc(2 * SET);
  float* Kb    = alloc(2 * SET);
  float* Vb    = alloc(2 * SET);
  float* attnb = alloc(2 * SET);
  float* msgb  = alloc(2 * SET);
  float* hb    = alloc((size_t)2 * B * 256 * N);
  float* stat  = alloc(2 * 256 * 2);
  float* la    = alloc((size_t)B * N * N);
  float* pmax  = alloc((size_t)B * 16 * N);
  float* psum  = alloc((size_t)B * 16 * N);
  float* cvec  = alloc((size_t)B * N);
  float* rvec  = alloc((size_t)B * N);
  float* rowsum= alloc((size_t)B * N);
  (void)ws_size; (void)in_sizes; (void)n_in; (void)out_size;

  auto conv = [&](const float* in0, const float* in1, const float* cat0,
                  const float* cat1, const float* w, const float* bias,
                  const float* res, float* out, int Cin, int catOff,
                  size_t in_bstr, size_t cat_bstr, int Cout) {
    dim3 g(N / 256, Cout / 16, 2 * B);
    k_conv<<<g, 256, 0, stream>>>(in0, in1, cat0, cat1, w, bias, res, out,
                                  Cin, catOff, in_bstr, cat_bstr, Cout);
  };

  k_norm2d<<<(B * N) / 256, 256, 0, stream>>>(p2d, f2);
  k_encode<<<dim3(N, B), 256, 0, stream>>>(f2, enc2d_w, enc2d_b, descA);
  k_encode<<<dim3(N, B), 256, 0, stream>>>(p3d, enc3d_w, enc3d_b, descA + SET);

  float* dc = descA;
  float* dn = descB;
  for (int i = 0; i < 6; ++i) {
    int cross = (i & 1);
    const float* pw = proj_w + (size_t)i * 3 * D * D;
    const float* pb = proj_b + (size_t)i * 3 * D;
    k_qkv<<<dim3(N / 256, 24, 2 * B), 256, 0, stream>>>(dc, pw, pb, Qb, Kb, Vb, cross);
    k_attn<<<dim3(N / 128, NH, 2 * B), 256, 0, stream>>>(Qb, Kb, Vb, attnb);
    conv(attnb, attnb + SET, nullptr, nullptr, merge_w + (size_t)i * D * D,
         merge_b + (size_t)i * D, nullptr, msgb, D, D, (size_t)D * N, 0, D);
    conv(dc, dc + SET, msgb, msgb + SET, mlp1_w + (size_t)i * 256 * 256,
         mlp1_b + (size_t)i * 256, nullptr, hb, 256, 128, (size_t)D * N,
         (size_t)D * N, 256);
    k_bnstat<<<dim3(256, 2), 256, 0, stream>>>(hb, stat);
    k_mlp2<<<dim3(N / 256, 8, 2 * B), 256, 0, stream>>>(
        hb, stat, bn_g + (size_t)i * 256, bn_b + (size_t)i * 256,
        mlp2_w + (size_t)i * D * 256, mlp2_b + (size_t)i * D, dc, dn);
    float* tmp = dc; dc = dn; dn = tmp;
  }

  k_dist<<<dim3(N / 8, B), 256, 0, stream>>>(dc, dc + SET, la);
  for (int it = 0; it < 10; ++it) {
    k_row_r<<<B * N, 256, 0, stream>>>(la, cvec, rvec, it > 0 ? 1 : 0);
    k_col_part<<<dim3(N / 256, 16, B), 256, 0, stream>>>(la, rvec, pmax, psum);
    k_col_fin<<<(B * N) / 256, 256, 0, stream>>>(pmax, psum, cvec);
  }
  k_rod<<<dim3(N / 256, B), 256, 0, stream>>>(pose, p3d, p3dt);
  k_err<<<dim3(N, B), 256, 0, stream>>>(la, rvec, cvec, f2, p3dt, rowsum);
  k_err_fin<<<B, 256, 0, stream>>>(rowsum, (float*)d_out);
}

// Round 9
// 1565.858 us; speedup vs baseline: 2.8915x; 1.3337x over previous
//
#include <hip/hip_runtime.h>
#include <hip/hip_bf16.h>

constexpr int B   = 4;
constexpr int N   = 1024;
constexpr int D   = 128;
constexpr int KNN = 10;
constexpr int NH  = 4;

// ---------------------------------------------------------------- norm p2d
__global__ __launch_bounds__(256) void k_norm2d(const float* __restrict__ p2d,
                                                float* __restrict__ f2) {
  int i = blockIdx.x * 256 + threadIdx.x;  // over B*N
  const float* p = p2d + (size_t)i * 3;
  float x = p[0], y = p[1], z = p[2];
  float inr = 1.f / sqrtf(x * x + y * y + z * z);
  float* o = f2 + (size_t)i * 3;
  o[0] = x * inr; o[1] = y * inr; o[2] = z * inr;
}

// ---------------------------------------------------------------- KNN encode
__global__ __launch_bounds__(256) void k_encode(const float* __restrict__ pts,
                                                const float* __restrict__ w,
                                                const float* __restrict__ bias,
                                                float* __restrict__ desc) {
  __shared__ float P[N][3];
  __shared__ float xx[N];
  __shared__ float dist[N];
  __shared__ float rv[256];
  __shared__ int   ri[256];
  __shared__ float feat[6];
  __shared__ int   nidx[KNN];
  int t = threadIdx.x;
  int n = blockIdx.x, b = blockIdx.y;
  const float* pb = pts + (size_t)b * N * 3;
  for (int i = t; i < N; i += 256) {
    float x = pb[i * 3 + 0], y = pb[i * 3 + 1], z = pb[i * 3 + 2];
    P[i][0] = x; P[i][1] = y; P[i][2] = z;
    xx[i] = x * x + y * y + z * z;
  }
  __syncthreads();
  float cx = P[n][0], cy = P[n][1], cz = P[n][2], cxx = xx[n];
  for (int i = t; i < N; i += 256) {
    float ip = cx * P[i][0] + cy * P[i][1] + cz * P[i][2];
    dist[i] = 2.f * ip - cxx - xx[i];
  }
  __syncthreads();
  for (int kk = 0; kk < KNN; ++kk) {
    float bv = -3.0e38f; int bi = N;
    for (int i = t; i < N; i += 256) {
      float v = dist[i];
      if (v > bv) { bv = v; bi = i; }
    }
    rv[t] = bv; ri[t] = bi;
    __syncthreads();
    for (int s = 128; s > 0; s >>= 1) {
      if (t < s) {
        float v2 = rv[t + s]; int i2 = ri[t + s];
        if (v2 > rv[t] || (v2 == rv[t] && i2 < ri[t])) { rv[t] = v2; ri[t] = i2; }
      }
      __syncthreads();
    }
    if (t == 0) { nidx[kk] = ri[0]; dist[ri[0]] = -3.0e38f; }
    __syncthreads();
  }
  if (t == 0) {
    float sx = 0, sy = 0, sz = 0;
    for (int kk = 0; kk < KNN; ++kk) {
      int i = nidx[kk];
      sx += P[i][0]; sy += P[i][1]; sz += P[i][2];
    }
    const float invk = 1.f / KNN;
    feat[0] = sx * invk - cx; feat[1] = sy * invk - cy; feat[2] = sz * invk - cz;
    feat[3] = cx; feat[4] = cy; feat[5] = cz;
  }
  __syncthreads();
  if (t < D) {
    const float* wr = w + t * 6;
    float a = bias[t];
#pragma unroll
    for (int j = 0; j < 6; ++j) a += wr[j] * feat[j];
    desc[((size_t)b * D + t) * N + n] = a;
  }
}

// ---------------------------------------------------------------- tiled GEMM conv
// out[seg? ][z][o][n] = W[o][c] * X[c][n] (+bias)(+res). BM=64 o, BN=128 n',
// BK=32, 256 thr, thread tile 4o x 8n. n' = z*1024+n flattened in grid.x (64).
// qkvMode: input = (seg==0 ? XA : XB); else channel c<catOff -> XA, >= -> XB.
// stat!=null: BN+ReLU transform applied to X at staging (coefs in LDS).
__global__ __launch_bounds__(256) void k_gemm(
    const float* __restrict__ pA0, const float* __restrict__ pA1,
    const float* __restrict__ pB0, const float* __restrict__ pB1,
    const float* __restrict__ w, const float* __restrict__ bias,
    const float* __restrict__ res, float* __restrict__ out,
    const float* __restrict__ stat, const float* __restrict__ g,
    const float* __restrict__ bt,
    int Cin, int catOff, size_t a_bstr, size_t b_bstr,
    int segCout, size_t segStride, int qkvMode) {
  __shared__ float As[64][36];     // W tile [o][c], pad 36 (16B-aligned rows)
  __shared__ float Bs[32][128];    // X tile [c][n]
  __shared__ float Ac[256], Bc[256];
  const int tid = threadIdx.x;
  const int to = tid >> 4;         // 0..15 -> 4 o each
  const int tn = tid & 15;         // 0..15 -> 8 n each
  const int o0 = blockIdx.y * 64;
  const int zb = blockIdx.x;       // 0..63
  const int z  = zb >> 3;
  const int n0 = (zb & 7) * 128;
  const int s = z >> 2, b = z & 3;
  const int seg = o0 / segCout;
  const int oo  = o0 % segCout;

  const float* XA = (s ? pA1 : pA0) + (size_t)b * a_bstr;
  const float* XB = pB0 ? ((s ? pB1 : pB0) + (size_t)b * b_bstr) : nullptr;
  const bool segB = qkvMode && (seg > 0);

  if (stat) {
    const float* st = stat + (size_t)s * 256 * 2;
    float A = st[tid * 2 + 1] * g[tid];
    Ac[tid] = A;
    Bc[tid] = fmaf(-st[tid * 2 + 0], A, bt[tid]);
  }

  float acc[4][8];
#pragma unroll
  for (int i = 0; i < 4; ++i)
#pragma unroll
    for (int j = 0; j < 8; ++j) acc[i][j] = 0.f;

  for (int kb = 0; kb < Cin; kb += 32) {
    __syncthreads();
    // stage W tile: 512 float4s, idx = j*256+tid -> o=idx/8, c4=(idx&7)*4
#pragma unroll
    for (int j = 0; j < 2; ++j) {
      int idx = j * 256 + tid;
      int o = idx >> 3, c4 = (idx & 7) * 4;
      float4 wv = *(const float4*)&w[(size_t)(o0 + o) * Cin + kb + c4];
      *(float4*)&As[o][c4] = wv;
    }
    // stage X tile: 1024 float4s, idx = j*256+tid -> r=idx/32, c4=(idx&31)*4
#pragma unroll
    for (int j = 0; j < 4; ++j) {
      int idx = j * 256 + tid;
      int r = idx >> 5, c4 = (idx & 31) * 4;
      int c = kb + r;
      const float* src;
      int cc = c;
      if (qkvMode) {
        src = segB ? XB : XA;
      } else if (c >= catOff) {
        src = XB; cc = c - catOff;
      } else {
        src = XA;
      }
      float4 v = *(const float4*)&src[(size_t)cc * N + n0 + c4];
      if (stat) {
        float A = Ac[c], Bb = Bc[c];
        v.x = fmaxf(fmaf(v.x, A, Bb), 0.f);
        v.y = fmaxf(fmaf(v.y, A, Bb), 0.f);
        v.z = fmaxf(fmaf(v.z, A, Bb), 0.f);
        v.w = fmaxf(fmaf(v.w, A, Bb), 0.f);
      }
      *(float4*)&Bs[r][c4] = v;
    }
    __syncthreads();
#pragma unroll
    for (int kk = 0; kk < 32; ++kk) {
      float af0 = As[to * 4 + 0][kk];
      float af1 = As[to * 4 + 1][kk];
      float af2 = As[to * 4 + 2][kk];
      float af3 = As[to * 4 + 3][kk];
      float4 b0 = *(const float4*)&Bs[kk][tn * 8];
      float4 b1 = *(const float4*)&Bs[kk][tn * 8 + 4];
      float bv[8] = {b0.x, b0.y, b0.z, b0.w, b1.x, b1.y, b1.z, b1.w};
#pragma unroll
      for (int j = 0; j < 8; ++j) {
        acc[0][j] = fmaf(af0, bv[j], acc[0][j]);
        acc[1][j] = fmaf(af1, bv[j], acc[1][j]);
        acc[2][j] = fmaf(af2, bv[j], acc[2][j]);
        acc[3][j] = fmaf(af3, bv[j], acc[3][j]);
      }
    }
  }
  // epilogue
#pragma unroll
  for (int i = 0; i < 4; ++i) {
    int og = o0 + to * 4 + i;              // global output row (bias index)
    int o  = oo + to * 4 + i;              // row within segment
    float bi = bias[og];
    size_t ob = (size_t)seg * segStride + ((size_t)z * segCout + o) * N + n0 + tn * 8;
    float4 r0, r1;
    r0.x = acc[i][0] + bi; r0.y = acc[i][1] + bi;
    r0.z = acc[i][2] + bi; r0.w = acc[i][3] + bi;
    r1.x = acc[i][4] + bi; r1.y = acc[i][5] + bi;
    r1.z = acc[i][6] + bi; r1.w = acc[i][7] + bi;
    if (res) {
      float4 e0 = *(const float4*)&res[ob];
      float4 e1 = *(const float4*)&res[ob + 4];
      r0.x += e0.x; r0.y += e0.y; r0.z += e0.z; r0.w += e0.w;
      r1.x += e1.x; r1.y += e1.y; r1.z += e1.z; r1.w += e1.w;
    }
    *(float4*)&out[ob] = r0;
    *(float4*)&out[ob + 4] = r1;
  }
}

// ---------------------------------------------------------------- attention v5 (116us verified)
// grid (N/128, NH, 2*B), 256 thr = 4 waves. Wave s owns keys [s*256,(s+1)*256).
// Each lane owns TWO queries. K/V chunks of 32 keys staged per-wave in LDS
// (contiguous float4 writes, broadcast b128 reads feed 8 FMAs); no barriers in
// the K-loop. R6: direct global loads 4.5x slower. R4: no min-waves bound.
__global__ __launch_bounds__(256) void k_attn(const float* __restrict__ Q,
                                              const float* __restrict__ Kt,
                                              const float* __restrict__ Vt,
                                              float* __restrict__ O) {
  __shared__ float pool[16896];
  __shared__ float ms_[4][128], ls_[4][128];
  const int t  = threadIdx.x;
  const int lq = t & 63, s = t >> 6;
  const int q0 = blockIdx.x * 128;
  const int h  = blockIdx.y;
  const int z  = blockIdx.z;
  const size_t base = (size_t)z * (size_t)(D * N);
  const float* Kb = Kt + base;
  const float* Vb = Vt + base;
  const int sb    = s * 2048;
  const int wrow  = lq >> 3;
  const int wslot = (lq & 7) * 4;

  const float scale = 0.17677669529663687f;
  float qA[32], qB[32], accA[32], accB[32];
#pragma unroll
  for (int d = 0; d < 32; ++d) {
    qA[d] = Q[base + (size_t)(d * 4 + h) * N + q0 + lq] * scale;
    qB[d] = Q[base + (size_t)(d * 4 + h) * N + q0 + 64 + lq] * scale;
    accA[d] = 0.f; accB[d] = 0.f;
  }
  float mxA = -1e30f, mxB = -1e30f, lA = 0.f, lB = 0.f;

  for (int c = 0; c < 8; ++c) {
    const int k0 = s * 256 + c * 32;
#pragma unroll
    for (int it = 0; it < 8; ++it) {
      int row = it * 8 + wrow;
      const float* src = (row < 32) ? (Kb + (size_t)(row * 4 + h) * N)
                                    : (Vb + (size_t)((row - 32) * 4 + h) * N);
      *(float4*)&pool[sb + row * 32 + wslot] = *(const float4*)(src + k0 + wslot);
    }
#pragma unroll
    for (int grp = 0; grp < 4; ++grp) {
      float scA[8], scB[8];
#pragma unroll
      for (int jg = 0; jg < 2; ++jg) {
        const int j0 = grp * 8 + jg * 4;
        float a0 = 0, a1 = 0, a2 = 0, a3 = 0, b0 = 0, b1 = 0, b2 = 0, b3 = 0;
#pragma unroll
        for (int d = 0; d < 32; ++d) {
          const float4 kv = *(const float4*)&pool[sb + d * 32 + j0];
          a0 = fmaf(qA[d], kv.x, a0); a1 = fmaf(qA[d], kv.y, a1);
          a2 = fmaf(qA[d], kv.z, a2); a3 = fmaf(qA[d], kv.w, a3);
          b0 = fmaf(qB[d], kv.x, b0); b1 = fmaf(qB[d], kv.y, b1);
          b2 = fmaf(qB[d], kv.z, b2); b3 = fmaf(qB[d], kv.w, b3);
        }
        scA[jg * 4 + 0] = a0; scA[jg * 4 + 1] = a1;
        scA[jg * 4 + 2] = a2; scA[jg * 4 + 3] = a3;
        scB[jg * 4 + 0] = b0; scB[jg * 4 + 1] = b1;
        scB[jg * 4 + 2] = b2; scB[jg * 4 + 3] = b3;
      }
      float hA = scA[0], hB = scB[0];
#pragma unroll
      for (int j = 1; j < 8; ++j) { hA = fmaxf(hA, scA[j]); hB = fmaxf(hB, scB[j]); }
      float nmA = fmaxf(mxA, hA), nmB = fmaxf(mxB, hB);
      float cA = __expf(mxA - nmA), cB = __expf(mxB - nmB);
      lA *= cA; lB *= cB;
#pragma unroll
      for (int d = 0; d < 32; ++d) { accA[d] *= cA; accB[d] *= cB; }
      mxA = nmA; mxB = nmB;
#pragma unroll
      for (int j = 0; j < 8; ++j) {
        scA[j] = __expf(scA[j] - mxA); lA += scA[j];
        scB[j] = __expf(scB[j] - mxB); lB += scB[j];
      }
#pragma unroll
      for (int jg = 0; jg < 2; ++jg) {
        const int j0 = grp * 8 + jg * 4;
        float pa0 = scA[jg * 4 + 0], pa1 = scA[jg * 4 + 1];
        float pa2 = scA[jg * 4 + 2], pa3 = scA[jg * 4 + 3];
        float pb0 = scB[jg * 4 + 0], pb1 = scB[jg * 4 + 1];
        float pb2 = scB[jg * 4 + 2], pb3 = scB[jg * 4 + 3];
#pragma unroll
        for (int d = 0; d < 32; ++d) {
          const float4 v = *(const float4*)&pool[sb + (32 + d) * 32 + j0];
          accA[d] = fmaf(pa0, v.x, fmaf(pa1, v.y, fmaf(pa2, v.z, fmaf(pa3, v.w, accA[d]))));
          accB[d] = fmaf(pb0, v.x, fmaf(pb1, v.y, fmaf(pb2, v.z, fmaf(pb3, v.w, accB[d]))));
        }
      }
    }
  }

  ms_[s][lq] = mxA; ms_[s][64 + lq] = mxB;
  ls_[s][lq] = lA;  ls_[s][64 + lq] = lB;
  __syncthreads();
#pragma unroll
  for (int d = 0; d < 32; ++d) {
    pool[(s * 128 + lq) * 33 + d] = accA[d];
    pool[(s * 128 + 64 + lq) * 33 + d] = accB[d];
  }
  __syncthreads();
  {
    int qq = t & 127, dh = t >> 7;
    float M = fmaxf(fmaxf(ms_[0][qq], ms_[1][qq]), fmaxf(ms_[2][qq], ms_[3][qq]));
    float wg[4], L = 0.f;
#pragma unroll
    for (int ss = 0; ss < 4; ++ss) {
      wg[ss] = __expf(ms_[ss][qq] - M);
      L += ls_[ss][qq] * wg[ss];
    }
    float invL = 1.f / L;
#pragma unroll
    for (int k = 0; k < 16; ++k) {
      int d = dh * 16 + k;
      float o = 0.f;
#pragma unroll
      for (int ss = 0; ss < 4; ++ss) o += pool[(ss * 128 + qq) * 33 + d] * wg[ss];
      O[base + (size_t)(d * 4 + h) * N + q0 + qq] = o * invL;
    }
  }
}

// ---------------------------------------------------------------- BN stats (single pass)
__global__ __launch_bounds__(256) void k_bnstat(const float* __restrict__ h,
                                                float* __restrict__ stat) {
  int c = blockIdx.x, s = blockIdx.y, t = threadIdx.x;
  __shared__ float red[256], red2[256];
  const float* base = h + ((size_t)s * B * 256 + c) * N;
  float sum = 0, sq = 0;
  for (int b = 0; b < B; ++b)
    for (int i = t; i < N; i += 256) {
      float v = base[(size_t)b * 256 * N + i];
      sum += v; sq = fmaf(v, v, sq);
    }
  red[t] = sum; red2[t] = sq; __syncthreads();
  for (int sft = 128; sft > 0; sft >>= 1) {
    if (t < sft) { red[t] += red[t + sft]; red2[t] += red2[t + sft]; }
    __syncthreads();
  }
  if (t == 0) {
    float mean = red[0] / (float)(B * N);
    float var = fmaxf(red2[0] / (float)(B * N) - mean * mean, 0.f);
    stat[(s * 256 + c) * 2 + 0] = mean;
    stat[(s * 256 + c) * 2 + 1] = 1.f / sqrtf(var + 1e-5f);
  }
}

// ---------------------------------------------------------------- pairwise dist (8-m tile)
__global__ __launch_bounds__(256) void k_dist(const float* __restrict__ d0,
                                              const float* __restrict__ d1,
                                              float* __restrict__ la) {
  __shared__ float xm[8][128];
  __shared__ float n0s[8];
  int m0 = blockIdx.x * 8, b = blockIdx.y, t = threadIdx.x;
  const float* p0 = d0 + (size_t)b * D * N;
  const float* p1 = d1 + (size_t)b * D * N;
  for (int i = t; i < 8 * 128; i += 256) {
    int mm = i >> 7, d = i & 127;
    xm[mm][d] = p0[(size_t)d * N + m0 + mm];
  }
  __syncthreads();
  if (t < 8) {
    float s = 0;
    for (int d = 0; d < 128; ++d) s += xm[t][d] * xm[t][d];
    n0s[t] = s;
  }
  __syncthreads();
  float dot[8][4] = {{0}};
  float n1[4] = {0, 0, 0, 0};
  for (int d = 0; d < 128; ++d) {
    float v[4];
#pragma unroll
    for (int u = 0; u < 4; ++u) {
      v[u] = p1[(size_t)d * N + t + u * 256];
      n1[u] = fmaf(v[u], v[u], n1[u]);
    }
#pragma unroll
    for (int mm = 0; mm < 8; ++mm) {
      float x = xm[mm][d];
#pragma unroll
      for (int u = 0; u < 4; ++u) dot[mm][u] = fmaf(x, v[u], dot[mm][u]);
    }
  }
  for (int mm = 0; mm < 8; ++mm) {
    float* row = la + ((size_t)b * N + m0 + mm) * N;
#pragma unroll
    for (int u = 0; u < 4; ++u) {
      float dist2 = fmaxf(n0s[mm] + n1[u] - 2.f * dot[mm][u], 1e-30f);
      row[t + u * 256] = -sqrtf(dist2);
    }
  }
}

// ---------------------------------------------------------------- sinkhorn offset form
// r[m] = LSE_n(l0[m,n] - c[n]); c[n] = LSE_m(l0[m,n] - r[m]). l0 never written.
__global__ __launch_bounds__(256) void k_row_r(const float* __restrict__ l0,
                                               const float* __restrict__ cvec,
                                               float* __restrict__ r,
                                               int useC) {
  __shared__ float red[256];
  int t = threadIdx.x;
  int bm = blockIdx.x;              // over B*N
  int b = bm >> 10;
  const float* row = l0 + (size_t)bm * N;
  float v0 = row[t], v1 = row[t + 256], v2 = row[t + 512], v3 = row[t + 768];
  if (useC) {
    const float* cl = cvec + (size_t)b * N;
    v0 -= cl[t]; v1 -= cl[t + 256]; v2 -= cl[t + 512]; v3 -= cl[t + 768];
  }
  float mx = fmaxf(fmaxf(v0, v1), fmaxf(v2, v3));
  red[t] = mx; __syncthreads();
  for (int s = 128; s > 0; s >>= 1) {
    if (t < s) red[t] = fmaxf(red[t], red[t + s]);
    __syncthreads();
  }
  mx = red[0]; __syncthreads();
  float se = __expf(v0 - mx) + __expf(v1 - mx) + __expf(v2 - mx) + __expf(v3 - mx);
  red[t] = se; __syncthreads();
  for (int s = 128; s > 0; s >>= 1) {
    if (t < s) red[t] += red[t + s];
    __syncthreads();
  }
  if (t == 0) r[bm] = mx + __logf(red[0]);
}

// 32 partials over m (512 blocks = 2/CU, serial loop halved vs 16)
__global__ __launch_bounds__(256) void k_col_part(const float* __restrict__ l0,
                                                  const float* __restrict__ r,
                                                  float* __restrict__ pmax,
                                                  float* __restrict__ psum) {
  int t = threadIdx.x;
  int n = blockIdx.x * 256 + t;
  int p = blockIdx.y, b = blockIdx.z;
  const float* base = l0 + ((size_t)b * N + p * 32) * N + n;
  const float* rr = r + (size_t)b * N + p * 32;
  float mx = -1e30f, s = 0;
  for (int m = 0; m < 32; ++m) {
    float v = base[(size_t)m * N] - rr[m];
    if (v > mx) { s = s * __expf(mx - v) + 1.f; mx = v; }
    else s += __expf(v - mx);
  }
  pmax[((size_t)b * 32 + p) * N + n] = mx;
  psum[((size_t)b * 32 + p) * N + n] = s;
}

__global__ __launch_bounds__(256) void k_col_fin(const float* __restrict__ pmax,
                                                 const float* __restrict__ psum,
                                                 float* __restrict__ cvec) {
  int i = blockIdx.x * 256 + threadIdx.x;  // over B*N
  int b = i / N, n = i % N;
  float mx = -1e30f;
#pragma unroll
  for (int p = 0; p < 32; ++p) mx = fmaxf(mx, pmax[((size_t)b * 32 + p) * N + n]);
  float s = 0;
#pragma unroll
  for (int p = 0; p < 32; ++p)
    s += psum[((size_t)b * 32 + p) * N + n] * __expf(pmax[((size_t)b * 32 + p) * N + n] - mx);
  cvec[i] = mx + __logf(s);
}

// ---------------------------------------------------------------- rodrigues + transform
__global__ __launch_bounds__(256) void k_rod(const float* __restrict__ pose,
                                             const float* __restrict__ p3d,
                                             float* __restrict__ p3dt) {
  int b = blockIdx.y;
  int n = blockIdx.x * 256 + threadIdx.x;
  const float* aa = pose + b * 6;
  float ax = aa[0], ay = aa[1], az = aa[2];
  float th = fmaxf(sqrtf(ax * ax + ay * ay + az * az), 1e-8f);
  float rx = ax / th, ry = ay / th, rz = az / th;
  float c = cosf(th), s = sinf(th), oc = 1.f - c;
  float R00 = c + oc * rx * rx,      R01 = oc * rx * ry - s * rz, R02 = oc * rx * rz + s * ry;
  float R10 = oc * ry * rx + s * rz, R11 = c + oc * ry * ry,      R12 = oc * ry * rz - s * rx;
  float R20 = oc * rz * rx - s * ry, R21 = oc * rz * ry + s * rx, R22 = c + oc * rz * rz;
  const float* p = p3d + ((size_t)b * N + n) * 3;
  float x = p[0], y = p[1], z = p[2];
  float X = R00 * x + R01 * y + R02 * z + aa[3];
  float Y = R10 * x + R11 * y + R12 * z + aa[4];
  float Z = R20 * x + R21 * y + R22 * z + aa[5];
  float inr = 1.f / sqrtf(X * X + Y * Y + Z * Z);
  float* o = p3dt + ((size_t)b * N + n) * 3;
  o[0] = X * inr; o[1] = Y * inr; o[2] = Z * inr;
}

// ---------------------------------------------------------------- final error (applies r,c offsets)
__global__ __launch_bounds__(256) void k_err(const float* __restrict__ l0,
                                             const float* __restrict__ r,
                                             const float* __restrict__ cvec,
                                             const float* __restrict__ f2,
                                             const float* __restrict__ p3dt,
                                             float* __restrict__ rowsum) {
  __shared__ float red[256];
  int m = blockIdx.x, b = blockIdx.y, t = threadIdx.x;
  const float* row = l0 + ((size_t)b * N + m) * N;
  const float* cl = cvec + (size_t)b * N;
  const float rm = r[(size_t)b * N + m];
  const float* f = f2 + ((size_t)b * N + m) * 3;
  float fx = f[0], fy = f[1], fz = f[2];
  float s = 0;
  for (int n = t; n < N; n += 256) {
    const float* pp = p3dt + ((size_t)b * N + n) * 3;
    float dot = fx * pp[0] + fy * pp[1] + fz * pp[2];
    s += __expf(row[n] - rm - cl[n]) * (1.f - dot);
  }
  red[t] = s; __syncthreads();
  for (int sft = 128; sft > 0; sft >>= 1) {
    if (t < sft) red[t] += red[t + sft];
    __syncthreads();
  }
  if (t == 0) rowsum[(size_t)b * N + m] = red[0];
}

__global__ __launch_bounds__(256) void k_err_fin(const float* __restrict__ rowsum,
                                                 float* __restrict__ out) {
  __shared__ float red[256];
  int b = blockIdx.x, t = threadIdx.x;
  float s = 0;
  for (int i = t; i < N; i += 256) s += rowsum[(size_t)b * N + i];
  red[t] = s; __syncthreads();
  for (int sft = 128; sft > 0; sft >>= 1) {
    if (t < sft) red[t] += red[t + sft];
    __syncthreads();
  }
  if (t == 0) out[b] = red[0];
}

// ================================================================= host
extern "C" void kernel_launch(void* const* d_in, const int* in_sizes, int n_in,
                              void* d_out, int out_size, void* d_ws, size_t ws_size,
                              hipStream_t stream) {
  const float* p2d     = (const float*)d_in[0];
  const float* p3d     = (const float*)d_in[1];
  const float* pose    = (const float*)d_in[2];
  const float* enc2d_w = (const float*)d_in[3];
  const float* enc2d_b = (const float*)d_in[4];
  const float* enc3d_w = (const float*)d_in[5];
  const float* enc3d_b = (const float*)d_in[6];
  const float* proj_w  = (const float*)d_in[7];
  const float* proj_b  = (const float*)d_in[8];
  const float* merge_w = (const float*)d_in[9];
  const float* merge_b = (const float*)d_in[10];
  const float* mlp1_w  = (const float*)d_in[11];
  const float* mlp1_b  = (const float*)d_in[12];
  const float* bn_g    = (const float*)d_in[13];
  const float* bn_b    = (const float*)d_in[14];
  const float* mlp2_w  = (const float*)d_in[15];
  const float* mlp2_b  = (const float*)d_in[16];

  float* W = (float*)d_ws;
  size_t off = 0;
  auto alloc = [&](size_t nelem) { float* p = W + off; off += nelem; return p; };
  const size_t SET = (size_t)B * D * N;          // one descriptor set
  float* f2    = alloc((size_t)B * N * 3);
  float* p3dt  = alloc((size_t)B * N * 3);
  float* descA = alloc(2 * SET);
  float* descB = alloc(2 * SET);
  float* qkv   = alloc(3 * 2 * SET);             // Q | K | V segments
  float* attnb = alloc(2 * SET);
  float* msgb  = alloc(2 * SET);
  float* hb    = alloc((size_t)2 * B * 256 * N);
  float* stat  = alloc(2 * 256 * 2);
  float* la    = alloc((size_t)B * N * N);
  float* pmax  = alloc((size_t)B * 32 * N);
  float* psum  = alloc((size_t)B * 32 * N);
  float* cvec  = alloc((size_t)B * N);
  float* rvec  = alloc((size_t)B * N);
  float* rowsum= alloc((size_t)B * N);
  (void)ws_size; (void)in_sizes; (void)n_in; (void)out_size;

  float* Qb = qkv;
  float* Kb = qkv + 2 * SET;
  float* Vb = qkv + 4 * SET;
  const size_t DS = (size_t)D * N;               // per-(set,b) panel stride

  k_norm2d<<<(B * N) / 256, 256, 0, stream>>>(p2d, f2);
  k_encode<<<dim3(N, B), 256, 0, stream>>>(f2, enc2d_w, enc2d_b, descA);
  k_encode<<<dim3(N, B), 256, 0, stream>>>(p3d, enc3d_w, enc3d_b, descA + SET);

  float* dc = descA;
  float* dn = descB;
  for (int i = 0; i < 6; ++i) {
    int cross = (i & 1);
    const float* pw = proj_w + (size_t)i * 3 * D * D;
    const float* pb = proj_b + (size_t)i * 3 * D;
    float* d0 = dc;
    float* d1 = dc + SET;
    const float* sA = cross ? d1 : d0;   // K/V source for set0
    const float* sB = cross ? d0 : d1;   // K/V source for set1

    // fused QKV: Cout=384 over 3 segments of 128; seg0 input = own set,
    // seg1/2 input = cross-selected source.
    k_gemm<<<dim3(64, 6), 256, 0, stream>>>(
        d0, d1, sA, sB, pw, pb, nullptr, qkv, nullptr, nullptr, nullptr,
        D, D, DS, DS, D, 2 * SET, 1);
    k_attn<<<dim3(N / 128, NH, 2 * B), 256, 0, stream>>>(Qb, Kb, Vb, attnb);
    // merge
    k_gemm<<<dim3(64, 2), 256, 0, stream>>>(
        attnb, attnb + SET, nullptr, nullptr, merge_w + (size_t)i * D * D,
        merge_b + (size_t)i * D, nullptr, msgb, nullptr, nullptr, nullptr,
        D, D, DS, DS, D, 0, 0);
    // mlp1: concat [desc ; msg]
    k_gemm<<<dim3(64, 4), 256, 0, stream>>>(
        dc, dc + SET, msgb, msgb + SET, mlp1_w + (size_t)i * 256 * 256,
        mlp1_b + (size_t)i * 256, nullptr, hb, nullptr, nullptr, nullptr,
        256, 128, DS, DS, 256, 0, 0);
    k_bnstat<<<dim3(256, 2), 256, 0, stream>>>(hb, stat);
    // mlp2: BN+ReLU folded into staging, residual add
    k_gemm<<<dim3(64, 2), 256, 0, stream>>>(
        hb, hb + (size_t)B * 256 * N, nullptr, nullptr,
        mlp2_w + (size_t)i * D * 256, mlp2_b + (size_t)i * D, dc, dn,
        stat, bn_g + (size_t)i * 256, bn_b + (size_t)i * 256,
        256, 256, (size_t)256 * N, 0, D, 0, 0);
    float* tmp = dc; dc = dn; dn = tmp;
  }

  k_dist<<<dim3(N / 8, B), 256, 0, stream>>>(dc, dc + SET, la);
  for (int it = 0; it < 10; ++it) {
    k_row_r<<<B * N, 256, 0, stream>>>(la, cvec, rvec, it > 0 ? 1 : 0);
    k_col_part<<<dim3(N / 256, 32, B), 256, 0, stream>>>(la, rvec, pmax, psum);
    k_col_fin<<<(B * N) / 256, 256, 0, stream>>>(pmax, psum, cvec);
  }
  k_rod<<<dim3(N / 256, B), 256, 0, stream>>>(pose, p3d, p3dt);
  k_err<<<dim3(N, B), 256, 0, stream>>>(la, rvec, cvec, f2, p3dt, rowsum);
  k_err_fin<<<B, 256, 0, stream>>>(rowsum, (float*)d_out);
}

// Round 11
// 1340.473 us; speedup vs baseline: 3.3777x; 1.1681x over previous
//
#include <hip/hip_runtime.h>
#include <hip/hip_bf16.h>

constexpr int B   = 4;
constexpr int N   = 1024;
constexpr int D   = 128;
constexpr int KNN = 10;
constexpr int NH  = 4;

typedef _Float16 half2v __attribute__((ext_vector_type(2)));

static __device__ __forceinline__ half2v pkrtz(float a, float b) {
  return __builtin_bit_cast(half2v, __builtin_amdgcn_cvt_pkrtz(a, b));
}

// ---------------------------------------------------------------- norm p2d
__global__ __launch_bounds__(256) void k_norm2d(const float* __restrict__ p2d,
                                                float* __restrict__ f2) {
  int i = blockIdx.x * 256 + threadIdx.x;  // over B*N
  const float* p = p2d + (size_t)i * 3;
  float x = p[0], y = p[1], z = p[2];
  float inr = 1.f / sqrtf(x * x + y * y + z * z);
  float* o = f2 + (size_t)i * 3;
  o[0] = x * inr; o[1] = y * inr; o[2] = z * inr;
}

// ---------------------------------------------------------------- KNN encode
__global__ __launch_bounds__(256) void k_encode(const float* __restrict__ pts,
                                                const float* __restrict__ w,
                                                const float* __restrict__ bias,
                                                float* __restrict__ desc) {
  __shared__ float P[N][3];
  __shared__ float xx[N];
  __shared__ float dist[N];
  __shared__ float rv[256];
  __shared__ int   ri[256];
  __shared__ float feat[6];
  __shared__ int   nidx[KNN];
  int t = threadIdx.x;
  int n = blockIdx.x, b = blockIdx.y;
  const float* pb = pts + (size_t)b * N * 3;
  for (int i = t; i < N; i += 256) {
    float x = pb[i * 3 + 0], y = pb[i * 3 + 1], z = pb[i * 3 + 2];
    P[i][0] = x; P[i][1] = y; P[i][2] = z;
    xx[i] = x * x + y * y + z * z;
  }
  __syncthreads();
  float cx = P[n][0], cy = P[n][1], cz = P[n][2], cxx = xx[n];
  for (int i = t; i < N; i += 256) {
    float ip = cx * P[i][0] + cy * P[i][1] + cz * P[i][2];
    dist[i] = 2.f * ip - cxx - xx[i];
  }
  __syncthreads();
  for (int kk = 0; kk < KNN; ++kk) {
    float bv = -3.0e38f; int bi = N;
    for (int i = t; i < N; i += 256) {
      float v = dist[i];
      if (v > bv) { bv = v; bi = i; }
    }
    rv[t] = bv; ri[t] = bi;
    __syncthreads();
    for (int s = 128; s > 0; s >>= 1) {
      if (t < s) {
        float v2 = rv[t + s]; int i2 = ri[t + s];
        if (v2 > rv[t] || (v2 == rv[t] && i2 < ri[t])) { rv[t] = v2; ri[t] = i2; }
      }
      __syncthreads();
    }
    if (t == 0) { nidx[kk] = ri[0]; dist[ri[0]] = -3.0e38f; }
    __syncthreads();
  }
  if (t == 0) {
    float sx = 0, sy = 0, sz = 0;
    for (int kk = 0; kk < KNN; ++kk) {
      int i = nidx[kk];
      sx += P[i][0]; sy += P[i][1]; sz += P[i][2];
    }
    const float invk = 1.f / KNN;
    feat[0] = sx * invk - cx; feat[1] = sy * invk - cy; feat[2] = sz * invk - cz;
    feat[3] = cx; feat[4] = cy; feat[5] = cz;
  }
  __syncthreads();
  if (t < D) {
    const float* wr = w + t * 6;
    float a = bias[t];
#pragma unroll
    for (int j = 0; j < 6; ++j) a += wr[j] * feat[j];
    desc[((size_t)b * D + t) * N + n] = a;
  }
}

// ---------------------------------------------------------------- tiled GEMM conv (unchanged from R9)
__global__ __launch_bounds__(256) void k_gemm(
    const float* __restrict__ pA0, const float* __restrict__ pA1,
    const float* __restrict__ pB0, const float* __restrict__ pB1,
    const float* __restrict__ w, const float* __restrict__ bias,
    const float* __restrict__ res, float* __restrict__ out,
    const float* __restrict__ stat, const float* __restrict__ g,
    const float* __restrict__ bt,
    int Cin, int catOff, size_t a_bstr, size_t b_bstr,
    int segCout, size_t segStride, int qkvMode) {
  __shared__ float As[64][36];
  __shared__ float Bs[32][128];
  __shared__ float Ac[256], Bc[256];
  const int tid = threadIdx.x;
  const int to = tid >> 4;
  const int tn = tid & 15;
  const int o0 = blockIdx.y * 64;
  const int zb = blockIdx.x;
  const int z  = zb >> 3;
  const int n0 = (zb & 7) * 128;
  const int s = z >> 2, b = z & 3;
  const int seg = o0 / segCout;
  const int oo  = o0 % segCout;

  const float* XA = (s ? pA1 : pA0) + (size_t)b * a_bstr;
  const float* XB = pB0 ? ((s ? pB1 : pB0) + (size_t)b * b_bstr) : nullptr;
  const bool segB = qkvMode && (seg > 0);

  if (stat) {
    const float* st = stat + (size_t)s * 256 * 2;
    float A = st[tid * 2 + 1] * g[tid];
    Ac[tid] = A;
    Bc[tid] = fmaf(-st[tid * 2 + 0], A, bt[tid]);
  }

  float acc[4][8];
#pragma unroll
  for (int i = 0; i < 4; ++i)
#pragma unroll
    for (int j = 0; j < 8; ++j) acc[i][j] = 0.f;

  for (int kb = 0; kb < Cin; kb += 32) {
    __syncthreads();
#pragma unroll
    for (int j = 0; j < 2; ++j) {
      int idx = j * 256 + tid;
      int o = idx >> 3, c4 = (idx & 7) * 4;
      float4 wv = *(const float4*)&w[(size_t)(o0 + o) * Cin + kb + c4];
      *(float4*)&As[o][c4] = wv;
    }
#pragma unroll
    for (int j = 0; j < 4; ++j) {
      int idx = j * 256 + tid;
      int r = idx >> 5, c4 = (idx & 31) * 4;
      int c = kb + r;
      const float* src;
      int cc = c;
      if (qkvMode) {
        src = segB ? XB : XA;
      } else if (c >= catOff) {
        src = XB; cc = c - catOff;
      } else {
        src = XA;
      }
      float4 v = *(const float4*)&src[(size_t)cc * N + n0 + c4];
      if (stat) {
        float A = Ac[c], Bb = Bc[c];
        v.x = fmaxf(fmaf(v.x, A, Bb), 0.f);
        v.y = fmaxf(fmaf(v.y, A, Bb), 0.f);
        v.z = fmaxf(fmaf(v.z, A, Bb), 0.f);
        v.w = fmaxf(fmaf(v.w, A, Bb), 0.f);
      }
      *(float4*)&Bs[r][c4] = v;
    }
    __syncthreads();
#pragma unroll
    for (int kk = 0; kk < 32; ++kk) {
      float af0 = As[to * 4 + 0][kk];
      float af1 = As[to * 4 + 1][kk];
      float af2 = As[to * 4 + 2][kk];
      float af3 = As[to * 4 + 3][kk];
      float4 b0 = *(const float4*)&Bs[kk][tn * 8];
      float4 b1 = *(const float4*)&Bs[kk][tn * 8 + 4];
      float bv[8] = {b0.x, b0.y, b0.z, b0.w, b1.x, b1.y, b1.z, b1.w};
#pragma unroll
      for (int j = 0; j < 8; ++j) {
        acc[0][j] = fmaf(af0, bv[j], acc[0][j]);
        acc[1][j] = fmaf(af1, bv[j], acc[1][j]);
        acc[2][j] = fmaf(af2, bv[j], acc[2][j]);
        acc[3][j] = fmaf(af3, bv[j], acc[3][j]);
      }
    }
  }
#pragma unroll
  for (int i = 0; i < 4; ++i) {
    int og = o0 + to * 4 + i;
    int o  = oo + to * 4 + i;
    float bi = bias[og];
    size_t ob = (size_t)seg * segStride + ((size_t)z * segCout + o) * N + n0 + tn * 8;
    float4 r0, r1;
    r0.x = acc[i][0] + bi; r0.y = acc[i][1] + bi;
    r0.z = acc[i][2] + bi; r0.w = acc[i][3] + bi;
    r1.x = acc[i][4] + bi; r1.y = acc[i][5] + bi;
    r1.z = acc[i][6] + bi; r1.w = acc[i][7] + bi;
    if (res) {
      float4 e0 = *(const float4*)&res[ob];
      float4 e1 = *(const float4*)&res[ob + 4];
      r0.x += e0.x; r0.y += e0.y; r0.z += e0.z; r0.w += e0.w;
      r1.x += e1.x; r1.y += e1.y; r1.z += e1.z; r1.w += e1.w;
    }
    *(float4*)&out[ob] = r0;
    *(float4*)&out[ob + 4] = r1;
  }
}

// ---------------------------------------------------------------- attention v7: f16 K/V + v_dot2
// Same macro-structure as v5 (verified 116us): grid (N/128, NH, 2*B), 4 waves,
// wave s owns keys [s*256,(s+1)*256), QPL=2, per-wave LDS staging, no K-loop
// barriers. NEW: K/V staged as packed f16 pairs; each ds_read_b128 now carries
// 8 values (vs 4 f32) feeding 8 v_dot2_f32_f16 -> LDS reads halve (the v5
// bottleneck). Softmax/accumulators stay f32. Layouts: K [32 key][16 dpair],
// V [32 d][16 keypair]; P packed to f16 per 8-key step via cvt_pkrtz.
__global__ __launch_bounds__(256) void k_attn(const float* __restrict__ Q,
                                              const float* __restrict__ Kt,
                                              const float* __restrict__ Vt,
                                              float* __restrict__ O) {
  __shared__ float pool[16896];          // staging (f16, first 4096 slots); merge f32
  __shared__ float ms_[4][128], ls_[4][128];
  half2v* pool2 = (half2v*)pool;
  const int t  = threadIdx.x;
  const int lq = t & 63, s = t >> 6;
  const int q0 = blockIdx.x * 128;
  const int h  = blockIdx.y;
  const int z  = blockIdx.z;
  const size_t base = (size_t)z * (size_t)(D * N);
  const float* Kb = Kt + base;
  const float* Vb = Vt + base;
  const int sb2 = s * 1024;             // per-wave region: K [0,512), V [512,1024)
  const int kg  = lq & 7;               // staging key-group (4 keys)
  const int dp  = lq >> 3;              // 0..7

  const float scale = 0.17677669529663687f;  // 1/sqrt(32), folded into q
  half2v qpA[16], qpB[16];
  float accA[32], accB[32];
#pragma unroll
  for (int dd = 0; dd < 16; ++dd) {
    float a0 = Q[base + (size_t)((2 * dd) * 4 + h) * N + q0 + lq] * scale;
    float a1 = Q[base + (size_t)((2 * dd + 1) * 4 + h) * N + q0 + lq] * scale;
    qpA[dd] = pkrtz(a0, a1);
    float b0 = Q[base + (size_t)((2 * dd) * 4 + h) * N + q0 + 64 + lq] * scale;
    float b1 = Q[base + (size_t)((2 * dd + 1) * 4 + h) * N + q0 + 64 + lq] * scale;
    qpB[dd] = pkrtz(b0, b1);
  }
#pragma unroll
  for (int d = 0; d < 32; ++d) { accA[d] = 0.f; accB[d] = 0.f; }
  float mxA = -1e30f, mxB = -1e30f, lA = 0.f, lB = 0.f;

  for (int c = 0; c < 8; ++c) {
    const int k0 = s * 256 + c * 32;
    // ---- stage K: Kh[j][dd] = (K[2dd][j], K[2dd+1][j]) f16
#pragma unroll
    for (int rep = 0; rep < 2; ++rep) {
      int dd = dp + rep * 8;
      const float4 va = *(const float4*)(Kb + (size_t)((2 * dd) * 4 + h) * N + k0 + kg * 4);
      const float4 vb = *(const float4*)(Kb + (size_t)((2 * dd + 1) * 4 + h) * N + k0 + kg * 4);
      pool2[sb2 + (kg * 4 + 0) * 16 + dd] = pkrtz(va.x, vb.x);
      pool2[sb2 + (kg * 4 + 1) * 16 + dd] = pkrtz(va.y, vb.y);
      pool2[sb2 + (kg * 4 + 2) * 16 + dd] = pkrtz(va.z, vb.z);
      pool2[sb2 + (kg * 4 + 3) * 16 + dd] = pkrtz(va.w, vb.w);
    }
    // ---- stage V: Vp[d][jp] = (V[2jp][d], V[2jp+1][d]) f16
#pragma unroll
    for (int rep = 0; rep < 4; ++rep) {
      int d = dp + rep * 8;
      const float4 vv = *(const float4*)(Vb + (size_t)(d * 4 + h) * N + k0 + kg * 4);
      int idx = sb2 + 512 + d * 16 + kg * 2;
      pool2[idx]     = pkrtz(vv.x, vv.y);
      pool2[idx + 1] = pkrtz(vv.z, vv.w);
    }
    // ---- 4 steps of 8 keys
#pragma unroll
    for (int st = 0; st < 4; ++st) {
      float scA[8], scB[8];
#pragma unroll
      for (int jj = 0; jj < 8; ++jj) {
        const int rb = sb2 + (st * 8 + jj) * 16;
        float a = 0.f, bq = 0.f;
#pragma unroll
        for (int r = 0; r < 4; ++r) {
          float4 raw = *(const float4*)&pool2[rb + r * 4];
          half2v k0h = __builtin_bit_cast(half2v, raw.x);
          half2v k1h = __builtin_bit_cast(half2v, raw.y);
          half2v k2h = __builtin_bit_cast(half2v, raw.z);
          half2v k3h = __builtin_bit_cast(half2v, raw.w);
          a  = __builtin_amdgcn_fdot2(k0h, qpA[r * 4 + 0], a,  false);
          a  = __builtin_amdgcn_fdot2(k1h, qpA[r * 4 + 1], a,  false);
          a  = __builtin_amdgcn_fdot2(k2h, qpA[r * 4 + 2], a,  false);
          a  = __builtin_amdgcn_fdot2(k3h, qpA[r * 4 + 3], a,  false);
          bq = __builtin_amdgcn_fdot2(k0h, qpB[r * 4 + 0], bq, false);
          bq = __builtin_amdgcn_fdot2(k1h, qpB[r * 4 + 1], bq, false);
          bq = __builtin_amdgcn_fdot2(k2h, qpB[r * 4 + 2], bq, false);
          bq = __builtin_amdgcn_fdot2(k3h, qpB[r * 4 + 3], bq, false);
        }
        scA[jj] = a; scB[jj] = bq;
      }
      // online softmax over these 8 keys (f32, as v5)
      float hA = scA[0], hB = scB[0];
#pragma unroll
      for (int j = 1; j < 8; ++j) { hA = fmaxf(hA, scA[j]); hB = fmaxf(hB, scB[j]); }
      float nmA = fmaxf(mxA, hA), nmB = fmaxf(mxB, hB);
      float cA = __expf(mxA - nmA), cB = __expf(mxB - nmB);
      lA *= cA; lB *= cB;
#pragma unroll
      for (int d = 0; d < 32; ++d) { accA[d] *= cA; accB[d] *= cB; }
      mxA = nmA; mxB = nmB;
#pragma unroll
      for (int j = 0; j < 8; ++j) {
        scA[j] = __expf(scA[j] - mxA); lA += scA[j];
        scB[j] = __expf(scB[j] - mxB); lB += scB[j];
      }
      // pack P to f16 (pair order matches Vp key-pairing)
      half2v pA2[4], pB2[4];
#pragma unroll
      for (int u = 0; u < 4; ++u) {
        pA2[u] = pkrtz(scA[2 * u], scA[2 * u + 1]);
        pB2[u] = pkrtz(scB[2 * u], scB[2 * u + 1]);
      }
      // PV: one b128 read = 8 keys at dim d
#pragma unroll
      for (int d = 0; d < 32; ++d) {
        float4 raw = *(const float4*)&pool2[sb2 + 512 + d * 16 + st * 4];
        half2v v0 = __builtin_bit_cast(half2v, raw.x);
        half2v v1 = __builtin_bit_cast(half2v, raw.y);
        half2v v2 = __builtin_bit_cast(half2v, raw.z);
        half2v v3 = __builtin_bit_cast(half2v, raw.w);
        float aa = accA[d];
        aa = __builtin_amdgcn_fdot2(v0, pA2[0], aa, false);
        aa = __builtin_amdgcn_fdot2(v1, pA2[1], aa, false);
        aa = __builtin_amdgcn_fdot2(v2, pA2[2], aa, false);
        aa = __builtin_amdgcn_fdot2(v3, pA2[3], aa, false);
        accA[d] = aa;
        float bb = accB[d];
        bb = __builtin_amdgcn_fdot2(v0, pB2[0], bb, false);
        bb = __builtin_amdgcn_fdot2(v1, pB2[1], bb, false);
        bb = __builtin_amdgcn_fdot2(v2, pB2[2], bb, false);
        bb = __builtin_amdgcn_fdot2(v3, pB2[3], bb, false);
        accB[d] = bb;
      }
    }
  }

  // ---- merge 4 key-split partials (f32, as v5)
  ms_[s][lq] = mxA; ms_[s][64 + lq] = mxB;
  ls_[s][lq] = lA;  ls_[s][64 + lq] = lB;
  __syncthreads();
#pragma unroll
  for (int d = 0; d < 32; ++d) {
    pool[(s * 128 + lq) * 33 + d] = accA[d];
    pool[(s * 128 + 64 + lq) * 33 + d] = accB[d];
  }
  __syncthreads();
  {
    int qq = t & 127, dh = t >> 7;
    float M = fmaxf(fmaxf(ms_[0][qq], ms_[1][qq]), fmaxf(ms_[2][qq], ms_[3][qq]));
    float wg[4], L = 0.f;
#pragma unroll
    for (int ss = 0; ss < 4; ++ss) {
      wg[ss] = __expf(ms_[ss][qq] - M);
      L += ls_[ss][qq] * wg[ss];
    }
    float invL = 1.f / L;
#pragma unroll
    for (int k = 0; k < 16; ++k) {
      int d = dh * 16 + k;
      float o = 0.f;
#pragma unroll
      for (int ss = 0; ss < 4; ++ss) o += pool[(ss * 128 + qq) * 33 + d] * wg[ss];
      O[base + (size_t)(d * 4 + h) * N + q0 + qq] = o * invL;
    }
  }
}

// ---------------------------------------------------------------- BN stats (single pass)
__global__ __launch_bounds__(256) void k_bnstat(const float* __restrict__ h,
                                                float* __restrict__ stat) {
  int c = blockIdx.x, s = blockIdx.y, t = threadIdx.x;
  __shared__ float red[256], red2[256];
  const float* base = h + ((size_t)s * B * 256 + c) * N;
  float sum = 0, sq = 0;
  for (int b = 0; b < B; ++b)
    for (int i = t; i < N; i += 256) {
      float v = base[(size_t)b * 256 * N + i];
      sum += v; sq = fmaf(v, v, sq);
    }
  red[t] = sum; red2[t] = sq; __syncthreads();
  for (int sft = 128; sft > 0; sft >>= 1) {
    if (t < sft) { red[t] += red[t + sft]; red2[t] += red2[t + sft]; }
    __syncthreads();
  }
  if (t == 0) {
    float mean = red[0] / (float)(B * N);
    float var = fmaxf(red2[0] / (float)(B * N) - mean * mean, 0.f);
    stat[(s * 256 + c) * 2 + 0] = mean;
    stat[(s * 256 + c) * 2 + 1] = 1.f / sqrtf(var + 1e-5f);
  }
}

// ---------------------------------------------------------------- pairwise dist (8-m tile)
__global__ __launch_bounds__(256) void k_dist(const float* __restrict__ d0,
                                              const float* __restrict__ d1,
                                              float* __restrict__ la) {
  __shared__ float xm[8][128];
  __shared__ float n0s[8];
  int m0 = blockIdx.x * 8, b = blockIdx.y, t = threadIdx.x;
  const float* p0 = d0 + (size_t)b * D * N;
  const float* p1 = d1 + (size_t)b * D * N;
  for (int i = t; i < 8 * 128; i += 256) {
    int mm = i >> 7, d = i & 127;
    xm[mm][d] = p0[(size_t)d * N + m0 + mm];
  }
  __syncthreads();
  if (t < 8) {
    float s = 0;
    for (int d = 0; d < 128; ++d) s += xm[t][d] * xm[t][d];
    n0s[t] = s;
  }
  __syncthreads();
  float dot[8][4] = {{0}};
  float n1[4] = {0, 0, 0, 0};
  for (int d = 0; d < 128; ++d) {
    float v[4];
#pragma unroll
    for (int u = 0; u < 4; ++u) {
      v[u] = p1[(size_t)d * N + t + u * 256];
      n1[u] = fmaf(v[u], v[u], n1[u]);
    }
#pragma unroll
    for (int mm = 0; mm < 8; ++mm) {
      float x = xm[mm][d];
#pragma unroll
      for (int u = 0; u < 4; ++u) dot[mm][u] = fmaf(x, v[u], dot[mm][u]);
    }
  }
  for (int mm = 0; mm < 8; ++mm) {
    float* row = la + ((size_t)b * N + m0 + mm) * N;
#pragma unroll
    for (int u = 0; u < 4; ++u) {
      float dist2 = fmaxf(n0s[mm] + n1[u] - 2.f * dot[mm][u], 1e-30f);
      row[t + u * 256] = -sqrtf(dist2);
    }
  }
}

// ---------------------------------------------------------------- sinkhorn offset form
__global__ __launch_bounds__(256) void k_row_r(const float* __restrict__ l0,
                                               const float* __restrict__ cvec,
                                               float* __restrict__ r,
                                               int useC) {
  __shared__ float red[256];
  int t = threadIdx.x;
  int bm = blockIdx.x;              // over B*N
  int b = bm >> 10;
  const float* row = l0 + (size_t)bm * N;
  float v0 = row[t], v1 = row[t + 256], v2 = row[t + 512], v3 = row[t + 768];
  if (useC) {
    const float* cl = cvec + (size_t)b * N;
    v0 -= cl[t]; v1 -= cl[t + 256]; v2 -= cl[t + 512]; v3 -= cl[t + 768];
  }
  float mx = fmaxf(fmaxf(v0, v1), fmaxf(v2, v3));
  red[t] = mx; __syncthreads();
  for (int s = 128; s > 0; s >>= 1) {
    if (t < s) red[t] = fmaxf(red[t], red[t + s]);
    __syncthreads();
  }
  mx = red[0]; __syncthreads();
  float se = __expf(v0 - mx) + __expf(v1 - mx) + __expf(v2 - mx) + __expf(v3 - mx);
  red[t] = se; __syncthreads();
  for (int s = 128; s > 0; s >>= 1) {
    if (t < s) red[t] += red[t + s];
    __syncthreads();
  }
  if (t == 0) r[bm] = mx + __logf(red[0]);
}

__global__ __launch_bounds__(256) void k_col_part(const float* __restrict__ l0,
                                                  const float* __restrict__ r,
                                                  float* __restrict__ pmax,
                                                  float* __restrict__ psum) {
  int t = threadIdx.x;
  int n = blockIdx.x * 256 + t;
  int p = blockIdx.y, b = blockIdx.z;
  const float* base = l0 + ((size_t)b * N + p * 32) * N + n;
  const float* rr = r + (size_t)b * N + p * 32;
  float mx = -1e30f, s = 0;
  for (int m = 0; m < 32; ++m) {
    float v = base[(size_t)m * N] - rr[m];
    if (v > mx) { s = s * __expf(mx - v) + 1.f; mx = v; }
    else s += __expf(v - mx);
  }
  pmax[((size_t)b * 32 + p) * N + n] = mx;
  psum[((size_t)b * 32 + p) * N + n] = s;
}

__global__ __launch_bounds__(256) void k_col_fin(const float* __restrict__ pmax,
                                                 const float* __restrict__ psum,
                                                 float* __restrict__ cvec) {
  int i = blockIdx.x * 256 + threadIdx.x;  // over B*N
  int b = i / N, n = i % N;
  float mx = -1e30f;
#pragma unroll
  for (int p = 0; p < 32; ++p) mx = fmaxf(mx, pmax[((size_t)b * 32 + p) * N + n]);
  float s = 0;
#pragma unroll
  for (int p = 0; p < 32; ++p)
    s += psum[((size_t)b * 32 + p) * N + n] * __expf(pmax[((size_t)b * 32 + p) * N + n] - mx);
  cvec[i] = mx + __logf(s);
}

// ---------------------------------------------------------------- rodrigues + transform
__global__ __launch_bounds__(256) void k_rod(const float* __restrict__ pose,
                                             const float* __restrict__ p3d,
                                             float* __restrict__ p3dt) {
  int b = blockIdx.y;
  int n = blockIdx.x * 256 + threadIdx.x;
  const float* aa = pose + b * 6;
  float ax = aa[0], ay = aa[1], az = aa[2];
  float th = fmaxf(sqrtf(ax * ax + ay * ay + az * az), 1e-8f);
  float rx = ax / th, ry = ay / th, rz = az / th;
  float c = cosf(th), s = sinf(th), oc = 1.f - c;
  float R00 = c + oc * rx * rx,      R01 = oc * rx * ry - s * rz, R02 = oc * rx * rz + s * ry;
  float R10 = oc * ry * rx + s * rz, R11 = c + oc * ry * ry,      R12 = oc * ry * rz - s * rx;
  float R20 = oc * rz * rx - s * ry, R21 = oc * rz * ry + s * rx, R22 = c + oc * rz * rz;
  const float* p = p3d + ((size_t)b * N + n) * 3;
  float x = p[0], y = p[1], z = p[2];
  float X = R00 * x + R01 * y + R02 * z + aa[3];
  float Y = R10 * x + R11 * y + R12 * z + aa[4];
  float Z = R20 * x + R21 * y + R22 * z + aa[5];
  float inr = 1.f / sqrtf(X * X + Y * Y + Z * Z);
  float* o = p3dt + ((size_t)b * N + n) * 3;
  o[0] = X * inr; o[1] = Y * inr; o[2] = Z * inr;
}

// ---------------------------------------------------------------- final error (applies r,c offsets)
__global__ __launch_bounds__(256) void k_err(const float* __restrict__ l0,
                                             const float* __restrict__ r,
                                             const float* __restrict__ cvec,
                                             const float* __restrict__ f2,
                                             const float* __restrict__ p3dt,
                                             float* __restrict__ rowsum) {
  __shared__ float red[256];
  int m = blockIdx.x, b = blockIdx.y, t = threadIdx.x;
  const float* row = l0 + ((size_t)b * N + m) * N;
  const float* cl = cvec + (size_t)b * N;
  const float rm = r[(size_t)b * N + m];
  const float* f = f2 + ((size_t)b * N + m) * 3;
  float fx = f[0], fy = f[1], fz = f[2];
  float s = 0;
  for (int n = t; n < N; n += 256) {
    const float* pp = p3dt + ((size_t)b * N + n) * 3;
    float dot = fx * pp[0] + fy * pp[1] + fz * pp[2];
    s += __expf(row[n] - rm - cl[n]) * (1.f - dot);
  }
  red[t] = s; __syncthreads();
  for (int sft = 128; sft > 0; sft >>= 1) {
    if (t < sft) red[t] += red[t + sft];
    __syncthreads();
  }
  if (t == 0) rowsum[(size_t)b * N + m] = red[0];
}

__global__ __launch_bounds__(256) void k_err_fin(const float* __restrict__ rowsum,
                                                 float* __restrict__ out) {
  __shared__ float red[256];
  int b = blockIdx.x, t = threadIdx.x;
  float s = 0;
  for (int i = t; i < N; i += 256) s += rowsum[(size_t)b * N + i];
  red[t] = s; __syncthreads();
  for (int sft = 128; sft > 0; sft >>= 1) {
    if (t < sft) red[t] += red[t + sft];
    __syncthreads();
  }
  if (t == 0) out[b] = red[0];
}

// ================================================================= host
extern "C" void kernel_launch(void* const* d_in, const int* in_sizes, int n_in,
                              void* d_out, int out_size, void* d_ws, size_t ws_size,
                              hipStream_t stream) {
  const float* p2d     = (const float*)d_in[0];
  const float* p3d     = (const float*)d_in[1];
  const float* pose    = (const float*)d_in[2];
  const float* enc2d_w = (const float*)d_in[3];
  const float* enc2d_b = (const float*)d_in[4];
  const float* enc3d_w = (const float*)d_in[5];
  const float* enc3d_b = (const float*)d_in[6];
  const float* proj_w  = (const float*)d_in[7];
  const float* proj_b  = (const float*)d_in[8];
  const float* merge_w = (const float*)d_in[9];
  const float* merge_b = (const float*)d_in[10];
  const float* mlp1_w  = (const float*)d_in[11];
  const float* mlp1_b  = (const float*)d_in[12];
  const float* bn_g    = (const float*)d_in[13];
  const float* bn_b    = (const float*)d_in[14];
  const float* mlp2_w  = (const float*)d_in[15];
  const float* mlp2_b  = (const float*)d_in[16];

  float* W = (float*)d_ws;
  size_t off = 0;
  auto alloc = [&](size_t nelem) { float* p = W + off; off += nelem; return p; };
  const size_t SET = (size_t)B * D * N;
  float* f2    = alloc((size_t)B * N * 3);
  float* p3dt  = alloc((size_t)B * N * 3);
  float* descA = alloc(2 * SET);
  float* descB = alloc(2 * SET);
  float* qkv   = alloc(3 * 2 * SET);
  float* attnb = alloc(2 * SET);
  float* msgb  = alloc(2 * SET);
  float* hb    = alloc((size_t)2 * B * 256 * N);
  float* stat  = alloc(2 * 256 * 2);
  float* la    = alloc((size_t)B * N * N);
  float* pmax  = alloc((size_t)B * 32 * N);
  float* psum  = alloc((size_t)B * 32 * N);
  float* cvec  = alloc((size_t)B * N);
  float* rvec  = alloc((size_t)B * N);
  float* rowsum= alloc((size_t)B * N);
  (void)ws_size; (void)in_sizes; (void)n_in; (void)out_size;

  float* Qb = qkv;
  float* Kb = qkv + 2 * SET;
  float* Vb = qkv + 4 * SET;
  const size_t DS = (size_t)D * N;

  k_norm2d<<<(B * N) / 256, 256, 0, stream>>>(p2d, f2);
  k_encode<<<dim3(N, B), 256, 0, stream>>>(f2, enc2d_w, enc2d_b, descA);
  k_encode<<<dim3(N, B), 256, 0, stream>>>(p3d, enc3d_w, enc3d_b, descA + SET);

  float* dc = descA;
  float* dn = descB;
  for (int i = 0; i < 6; ++i) {
    int cross = (i & 1);
    const float* pw = proj_w + (size_t)i * 3 * D * D;
    const float* pb = proj_b + (size_t)i * 3 * D;
    float* d0 = dc;
    float* d1 = dc + SET;
    const float* sA = cross ? d1 : d0;
    const float* sB = cross ? d0 : d1;

    k_gemm<<<dim3(64, 6), 256, 0, stream>>>(
        d0, d1, sA, sB, pw, pb, nullptr, qkv, nullptr, nullptr, nullptr,
        D, D, DS, DS, D, 2 * SET, 1);
    k_attn<<<dim3(N / 128, NH, 2 * B), 256, 0, stream>>>(Qb, Kb, Vb, attnb);
    k_gemm<<<dim3(64, 2), 256, 0, stream>>>(
        attnb, attnb + SET, nullptr, nullptr, merge_w + (size_t)i * D * D,
        merge_b + (size_t)i * D, nullptr, msgb, nullptr, nullptr, nullptr,
        D, D, DS, DS, D, 0, 0);
    k_gemm<<<dim3(64, 4), 256, 0, stream>>>(
        dc, dc + SET, msgb, msgb + SET, mlp1_w + (size_t)i * 256 * 256,
        mlp1_b + (size_t)i * 256, nullptr, hb, nullptr, nullptr, nullptr,
        256, 128, DS, DS, 256, 0, 0);
    k_bnstat<<<dim3(256, 2), 256, 0, stream>>>(hb, stat);
    k_gemm<<<dim3(64, 2), 256, 0, stream>>>(
        hb, hb + (size_t)B * 256 * N, nullptr, nullptr,
        mlp2_w + (size_t)i * D * 256, mlp2_b + (size_t)i * D, dc, dn,
        stat, bn_g + (size_t)i * 256, bn_b + (size_t)i * 256,
        256, 256, (size_t)256 * N, 0, D, 0, 0);
    float* tmp = dc; dc = dn; dn = tmp;
  }

  k_dist<<<dim3(N / 8, B), 256, 0, stream>>>(dc, dc + SET, la);
  for (int it = 0; it < 10; ++it) {
    k_row_r<<<B * N, 256, 0, stream>>>(la, cvec, rvec, it > 0 ? 1 : 0);
    k_col_part<<<dim3(N / 256, 32, B), 256, 0, stream>>>(la, rvec, pmax, psum);
    k_col_fin<<<(B * N) / 256, 256, 0, stream>>>(pmax, psum, cvec);
  }
  k_rod<<<dim3(N / 256, B), 256, 0, stream>>>(pose, p3d, p3dt);
  k_err<<<dim3(N, B), 256, 0, stream>>>(la, rvec, cvec, f2, p3dt, rowsum);
  k_err_fin<<<B, 256, 0, stream>>>(rowsum, (float*)d_out);
}